// Round 1
// baseline (572.594 us; speedup 1.0000x reference)
//
#include <hip/hip_runtime.h>
#include <stdint.h>

// ---- problem constants (from setup_inputs) ----
static constexpr int NV   = 80000;    // voxels per scale
static constexpr int NPT  = 240000;   // points N
static constexpr int NIMG = 60000;    // B*M image-projected points
static constexpr int Hh   = 64;
static constexpr int Cc   = 20;
static constexpr int NPp  = 120000;   // N per batch
static constexpr int Mm   = 30000;
static constexpr int NB     = 8192;   // error-histogram bins (top-15 float bits)
static constexpr int NCH    = 16;     // chunks per class in hist kernel
static constexpr int NBLK_GA  = (NIMG + 63) / 64;   // 938 gemm_att blocks
static constexpr int NBLK_MLP = NV / 64;            // 1250 pred3d-mlp blocks
static constexpr int NBLK_CNT = (NPT + 255) / 256;  // 938 counts/idx blocks
#define BN_EPS 1e-5f

using bf16x8 = __attribute__((ext_vector_type(8))) short;
using f32x4  = __attribute__((ext_vector_type(4))) float;

// ================= small helpers =================
__device__ __forceinline__ float waveReduce(float v) {
  #pragma unroll
  for (int o = 32; o > 0; o >>= 1) v += __shfl_down(v, o);
  return v;
}
__device__ __forceinline__ short f2bf(float f) {   // RNE fp32 -> bf16
  uint32_t u = __float_as_uint(f);
  return (short)((u + 0x7FFFu + ((u >> 16) & 1u)) >> 16);
}
__device__ __forceinline__ float bf2f(uint32_t h) { return __uint_as_float(h << 16); }
__device__ __forceinline__ uint32_t pk2(float a, float b) {
  return ((uint32_t)(uint16_t)f2bf(a)) | ((uint32_t)(uint16_t)f2bf(b) << 16);
}

// ================= weight pre-pack into MFMA B-frag order (+attEff) ========
struct PackDesc { const float* src; short* dst; int K, Nr, nt; };
struct PackArgs { PackDesc d[14]; };

__global__ void k_pack(PackArgs pa,
                       const float* __restrict__ fc1w, const float* __restrict__ fc1b,
                       const float* __restrict__ fc2w, const float* __restrict__ fc2b,
                       const float* __restrict__ fc3w, const float* __restrict__ fc3b,
                       float* __restrict__ attEffs) {
  int stride = gridDim.x * blockDim.x;
  for (int di = 0; di < 14; di++) {
    const float* src = pa.d[di].src;
    short* dst = pa.d[di].dst;
    int K = pa.d[di].K, Nr = pa.d[di].Nr, ntiles = pa.d[di].nt;
    int total = (K / 32) * ntiles * 512;
    for (int idx = blockIdx.x * blockDim.x + threadIdx.x; idx < total; idx += stride) {
      int j = idx & 7, lane = (idx >> 3) & 63, tile = idx >> 9;
      int nt = tile % ntiles, kt = tile / ntiles;
      int k = kt * 32 + (lane >> 4) * 8 + j;
      int n = nt * 16 + (lane & 15);
      float v = (n < Nr) ? src[(size_t)k * Nr + n] : 0.f;
      dst[idx] = f2bf(v);
    }
  }
  if (blockIdx.x < 2 && threadIdx.x < 64) {
    int s = blockIdx.x, t = threadIdx.x;
    const float* f1w = fc1w + s * 64 * 16; const float* f1b = fc1b + s * 16;
    const float* f2w = fc2w + s * 64 * 16; const float* f2b = fc2b + s * 16;
    const float* f3w = fc3w + s * 64;      const float* f3b = fc3b + s * 2;
    float* aE = attEffs + s * 320;
    float p0 = 0.f, p1 = 0.f, v0 = 0.f, v1 = 0.f;
    #pragma unroll
    for (int j = 0; j < 16; j++) {
      p0 = fmaf(f1w[t * 16 + j], f3w[j * 2], p0);
      p1 = fmaf(f1w[t * 16 + j], f3w[j * 2 + 1], p1);
      v0 = fmaf(f2w[t * 16 + j], f3w[(16 + j) * 2], v0);
      v1 = fmaf(f2w[t * 16 + j], f3w[(16 + j) * 2 + 1], v1);
    }
    aE[t * 2] = p0; aE[t * 2 + 1] = p1;
    aE[128 + t * 2] = v0; aE[128 + t * 2 + 1] = v1;
    if (t == 0) {
      float b0 = f3b[0], b1 = f3b[1];
      for (int j = 0; j < 16; j++) {
        b0 += f1b[j] * f3w[j * 2] + f2b[j] * f3w[(16 + j) * 2];
        b1 += f1b[j] * f3w[j * 2 + 1] + f2b[j] * f3w[(16 + j) * 2 + 1];
      }
      aE[256] = b0; aE[257] = b1;
    }
  }
}

// ====== Lovász scan+bin body: register-resident, wave-scan (self-cleaning) ==
// Thread t owns bins [t*32, t*32+32). Pass1: local sums. Wave scan (shfl_up)
// + 4-wave LDS combine -> exclusive prefix + Ftot. Pass2: reload bins (L2-hot),
// walk with running prefix, zero-store (self-clean).
__device__ void scanbin_body(uint32_t* __restrict__ Hb, uint32_t* __restrict__ HFb,
                             int n, int call, float* __restrict__ lossesC5,
                             int* __restrict__ gts5, int cls) {
  __shared__ int sWC[4], sWF[4];
  __shared__ float sRedF[4];
  int t = threadIdx.x;
  int lane = t & 63, w = t >> 6;
  uint32_t* Hc  = Hb  + (size_t)cls * NB;
  uint32_t* HFc = HFb + (size_t)cls * NB;
  int locC = 0, locF = 0;
  #pragma unroll
  for (int i = 0; i < 8; i++) {
    uint4 cv = *(const uint4*)(Hc  + t * 32 + i * 4);
    uint4 fv = *(const uint4*)(HFc + t * 32 + i * 4);
    locC += (int)(cv.x + cv.y + cv.z + cv.w);
    locF += (int)(fv.x + fv.y + fv.z + fv.w);
  }
  int sc = locC, sf = locF;
  #pragma unroll
  for (int o = 1; o < 64; o <<= 1) {
    int a = __shfl_up(sc, o);
    int b = __shfl_up(sf, o);
    if (lane >= o) { sc += a; sf += b; }
  }
  if (lane == 63) { sWC[w] = sc; sWF[w] = sf; }
  __syncthreads();
  int offC = 0, offF = 0, Ftot = 0;
  #pragma unroll
  for (int ww = 0; ww < 4; ww++) {
    int fc = sWF[ww];
    Ftot += fc;
    if (ww < w) { offC += sWC[ww]; offF += fc; }
  }
  int runC = offC + sc - locC;    // exclusive prefix (ascending bins)
  int runF = offF + sf - locF;
  float gts = (float)Ftot;
  float contrib = 0.f;
  const uint4 z = make_uint4(0u, 0u, 0u, 0u);
  #pragma unroll
  for (int i = 0; i < 8; i++) {
    uint4 cv = *(const uint4*)(Hc  + t * 32 + i * 4);
    uint4 fv = *(const uint4*)(HFc + t * 32 + i * 4);
    *(uint4*)(Hc  + t * 32 + i * 4) = z;                 // self-clean
    *(uint4*)(HFc + t * 32 + i * 4) = z;
    uint32_t ca[4] = {cv.x, cv.y, cv.z, cv.w};
    uint32_t fa[4] = {fv.x, fv.y, fv.z, fv.w};
    #pragma unroll
    for (int j = 0; j < 4; j++) {
      int cnt = (int)ca[j], fgc = (int)fa[j];
      runC += cnt; runF += fgc;                          // ascending inclusive
      if (cnt > 0 && Ftot > 0) {
        float r0 = (float)(n - runC);                    // elements with larger err
        float F0 = (float)(Ftot - runF);
        float r1 = r0 + (float)cnt;
        float F1 = F0 + (float)fgc;
        float emean = __uint_as_float((uint32_t)(t * 32 + i * 4 + j) << 17);
        contrib += emean * (r1 / (gts + r1 - F1) - r0 / (gts + r0 - F0));
      }
    }
  }
  contrib = waveReduce(contrib);
  if (lane == 0) sRedF[w] = contrib;
  __syncthreads();
  if (t == 0) {
    lossesC5[call * 32 + cls] = (Ftot > 0) ? (sRedF[0] + sRedF[1] + sRedF[2] + sRedF[3]) : 0.f;
    gts5[call * 32 + cls] = Ftot;
  }
}

__global__ void __launch_bounds__(256)
k_scanbin5(uint32_t* __restrict__ Hb, uint32_t* __restrict__ HFb, int n, int call,
           float* __restrict__ lossesC5, int* __restrict__ gts5) {
  scanbin_body(Hb, HFb, n, call, lossesC5, gts5, blockIdx.x);
}

// ================= MFMA MLP body: relu(X@W1+b1)@W2+b2 ====================
template<int D>
__device__ __forceinline__ void mfma_mlp_body(const short* sXb, short* sH,
    int r0, int rows,
    const short* __restrict__ pw1, const float* __restrict__ B1,
    const short* __restrict__ pw2, const float* __restrict__ B2,
    float* __restrict__ Out) {
  constexpr int LDB = D + 8;
  constexpr int KT1 = D / 32;
  const int t = threadIdx.x;
  const int lane = t & 63, w = t >> 6;
  const int m = lane & 15, quad = lane >> 4;
  const int rowA = 16 * w + m;
  bf16x8 a1[KT1];
  #pragma unroll
  for (int kt = 0; kt < KT1; kt++)
    a1[kt] = *(const bf16x8*)(sXb + rowA * LDB + kt * 32 + quad * 8);
  const bf16x8* b1 = (const bf16x8*)pw1;
  #pragma unroll
  for (int nt = 0; nt < 8; nt++) {
    f32x4 c = {0.f, 0.f, 0.f, 0.f};
    #pragma unroll
    for (int kt = 0; kt < KT1; kt++)
      c = __builtin_amdgcn_mfma_f32_16x16x32_bf16(a1[kt], b1[(kt * 8 + nt) * 64 + lane], c, 0, 0, 0);
    int col = nt * 16 + m;
    float bc = B1[col];
    #pragma unroll
    for (int reg = 0; reg < 4; reg++)
      sH[(16 * w + quad * 4 + reg) * 136 + col] = f2bf(fmaxf(c[reg] + bc, 0.f));
  }
  __syncthreads();
  bf16x8 a2[4];
  #pragma unroll
  for (int kt = 0; kt < 4; kt++)
    a2[kt] = *(const bf16x8*)(sH + rowA * 136 + kt * 32 + quad * 8);
  const bf16x8* b2 = (const bf16x8*)pw2;
  #pragma unroll
  for (int nt = 0; nt < 2; nt++) {
    f32x4 c = {0.f, 0.f, 0.f, 0.f};
    #pragma unroll
    for (int kt = 0; kt < 4; kt++)
      c = __builtin_amdgcn_mfma_f32_16x16x32_bf16(a2[kt], b2[(kt * 2 + nt) * 64 + lane], c, 0, 0, 0);
    int col = nt * 16 + m;
    if (col < Cc) {
      float bc = B2[col];
      #pragma unroll
      for (int reg = 0; reg < 4; reg++) {
        int gr = r0 + 16 * w + quad * 4 + reg;
        if (gr < rows) Out[(size_t)gr * Cc + col] = c[reg] + bc;
      }
    }
  }
}

// ========== fused bundle A: [scanbin(prev)] + pred3d MLP + counts/idx ======
template<bool WITH_SCAN>
__global__ void __launch_bounds__(256)
k_scale_start(const float* __restrict__ X,
              const short* __restrict__ pw1, const float* __restrict__ B1,
              const short* __restrict__ pw2, const float* __restrict__ B2,
              float* __restrict__ Out,
              const int* __restrict__ ci, const int* __restrict__ labels,
              int* __restrict__ counts, const int* __restrict__ p2img,
              int* __restrict__ idx,
              uint32_t* __restrict__ Hb, uint32_t* __restrict__ HFb, int callScan,
              float* __restrict__ lossesC5, int* __restrict__ gts5) {
  int bid = blockIdx.x;
  if (WITH_SCAN) {
    if (bid < Cc) { scanbin_body(Hb, HFb, NIMG, callScan, lossesC5, gts5, bid); return; }
    bid -= Cc;
  }
  if (bid < NBLK_MLP) {
    __shared__ __align__(16) short sXb[64 * 72];
    __shared__ __align__(16) short sH[64 * 136];
    int t = threadIdx.x, r0 = bid * 64;
    for (int i = t; i < 1024; i += 256) {     // NV % 64 == 0: no row guard
      int r = i >> 4, k4 = (i & 15) * 4;
      float4 v = *(const float4*)(X + (size_t)(r0 + r) * 64 + k4);
      uint2 p; p.x = pk2(v.x, v.y); p.y = pk2(v.z, v.w);
      *(uint2*)(sXb + r * 72 + k4) = p;
    }
    __syncthreads();
    mfma_mlp_body<64>(sXb, sH, r0, NV, pw1, B1, pw2, B2, Out);
  } else {
    int i = (bid - NBLK_MLP) * 256 + threadIdx.x;
    if (i < NIMG) {
      int b = (i >= Mm) ? 1 : 0;               // B=2, contiguous batch blocks
      idx[i] = ci[b * NPp + p2img[i]];
    }
    if (i < NPT) atomicAdd(&counts[(size_t)ci[i] * Cc + labels[i]], 1);
  }
}

// ================= fused BN+att fuse -> feats(bf16) + fuse-MLP (MFMA) ======
__global__ void __launch_bounds__(256)
k_fusemlp(const uint16_t* __restrict__ y1, const uint16_t* __restrict__ y2,
          const float* __restrict__ attw, const float* __restrict__ bnpar,
          uint16_t* __restrict__ feats, int s64,
          const short* __restrict__ pw1, const float* __restrict__ B1,
          const short* __restrict__ pw2, const float* __restrict__ B2,
          float* __restrict__ Out) {
  __shared__ __align__(16) short sXb[64 * 72];
  __shared__ __align__(16) short sH[64 * 136];
  int t = threadIdx.x, r0 = blockIdx.x * 64;
  for (int i = t; i < 1024; i += 256) {
    int r = i >> 4, q = i & 15;
    int gr = r0 + r;
    uint2 zp = make_uint2(0u, 0u);
    if (gr < NIMG) {
      float4 a1 = *(const float4*)(bnpar + q * 4);
      float4 c1 = *(const float4*)(bnpar + 64 + q * 4);
      float4 a2 = *(const float4*)(bnpar + 128 + q * 4);
      float4 c2 = *(const float4*)(bnpar + 192 + q * 4);
      uint2 u1 = *(const uint2*)(y1 + (size_t)gr * 64 + q * 4);
      uint2 u2 = *(const uint2*)(y2 + (size_t)gr * 64 + q * 4);
      float w0 = attw[gr * 2], w1 = attw[gr * 2 + 1];
      float zx = fmaxf(fmaf(bf2f(u1.x & 0xffff), a1.x, c1.x), 0.f) * w0
               + fmaxf(fmaf(bf2f(u2.x & 0xffff), a2.x, c2.x), 0.f) * w1;
      float zy = fmaxf(fmaf(bf2f(u1.x >> 16),   a1.y, c1.y), 0.f) * w0
               + fmaxf(fmaf(bf2f(u2.x >> 16),   a2.y, c2.y), 0.f) * w1;
      float zz = fmaxf(fmaf(bf2f(u1.y & 0xffff), a1.z, c1.z), 0.f) * w0
               + fmaxf(fmaf(bf2f(u2.y & 0xffff), a2.z, c2.z), 0.f) * w1;
      float zw = fmaxf(fmaf(bf2f(u1.y >> 16),   a1.w, c1.w), 0.f) * w0
               + fmaxf(fmaf(bf2f(u2.y >> 16),   a2.w, c2.w), 0.f) * w1;
      zp.x = pk2(zx, zy); zp.y = pk2(zz, zw);
      *(uint2*)(feats + (size_t)gr * 128 + s64 + q * 4) = zp;
    }
    *(uint2*)(sXb + r * 72 + q * 4) = zp;
  }
  __syncthreads();
  mfma_mlp_body<64>(sXb, sH, r0, NIMG, pw1, B1, pw2, B2, Out);
}

// == fused bundle B: scanbin(pred3d) + gather/GEMM/att + BN-stats atomics ==
// BN partials accumulated with unsafeAtomicAdd into bnAcc[256]; last gemm
// block (atomic ticket, fenced) computes bnpar in-kernel and self-cleans.
__global__ void __launch_bounds__(256)
k_gatt(const float* __restrict__ pts, const int* __restrict__ idx,
       const float* __restrict__ img,
       const short* __restrict__ pc1, const float* __restrict__ c1b,
       const short* __restrict__ pc2, const float* __restrict__ c2b,
       const float* __restrict__ attEff,
       uint16_t* __restrict__ y1, uint16_t* __restrict__ y2,
       float* __restrict__ attw,
       float* __restrict__ bnAcc, int* __restrict__ ctr,
       const float* __restrict__ g1, const float* __restrict__ be1,
       const float* __restrict__ g2, const float* __restrict__ be2,
       float* __restrict__ bnpar,
       uint32_t* __restrict__ Hb, uint32_t* __restrict__ HFb, int callScan,
       float* __restrict__ lossesC5, int* __restrict__ gts5) {
  if (blockIdx.x < Cc) {
    scanbin_body(Hb, HFb, NV, callScan, lossesC5, gts5, blockIdx.x);
    return;
  }
  __shared__ __align__(16) short sP[64 * 72], sV[64 * 72];
  __shared__ float sAtt[64 * 8];
  __shared__ float sStat[1024];        // [w][nt][kind][m]
  __shared__ int sLast;
  int t = threadIdx.x;
  int r0 = (blockIdx.x - Cc) * 64;
  for (int i = t; i < 1024; i += 256) {
    int r = i >> 4, q = i & 15;
    int gr = r0 + r;
    float4 vp = make_float4(0.f, 0.f, 0.f, 0.f), vv = vp;
    if (gr < NIMG) {
      vp = *(const float4*)(pts + (size_t)idx[gr] * 64 + q * 4);
      vv = *(const float4*)(img + (size_t)gr * 64 + q * 4);
    }
    uint2 pp, qv;
    pp.x = pk2(vp.x, vp.y); pp.y = pk2(vp.z, vp.w);
    qv.x = pk2(vv.x, vv.y); qv.y = pk2(vv.z, vv.w);
    *(uint2*)(sP + r * 72 + q * 4) = pp;
    *(uint2*)(sV + r * 72 + q * 4) = qv;
  }
  __syncthreads();
  {
    int r = t & 63, qq = t >> 6;
    const float* aP = attEff;
    const float* aV = attEff + 128;
    float l0 = 0.f, l1 = 0.f;
    for (int k = qq * 16; k < qq * 16 + 16; k += 4) {
      uint2 up = *(const uint2*)(sP + r * 72 + k);
      uint2 uv = *(const uint2*)(sV + r * 72 + k);
      float p0 = bf2f(up.x & 0xffff), p1 = bf2f(up.x >> 16);
      float p2 = bf2f(up.y & 0xffff), p3 = bf2f(up.y >> 16);
      float v0 = bf2f(uv.x & 0xffff), v1 = bf2f(uv.x >> 16);
      float v2 = bf2f(uv.y & 0xffff), v3 = bf2f(uv.y >> 16);
      float4 wa = *(const float4*)(aP + 2 * k);
      float4 wb = *(const float4*)(aP + 2 * k + 4);
      l0 += p0 * wa.x + p1 * wa.z + p2 * wb.x + p3 * wb.z;
      l1 += p0 * wa.y + p1 * wa.w + p2 * wb.y + p3 * wb.w;
      float4 ua = *(const float4*)(aV + 2 * k);
      float4 ub = *(const float4*)(aV + 2 * k + 4);
      l0 += v0 * ua.x + v1 * ua.z + v2 * ub.x + v3 * ub.z;
      l1 += v0 * ua.y + v1 * ua.w + v2 * ub.y + v3 * ub.w;
    }
    sAtt[r * 8 + qq * 2] = l0;
    sAtt[r * 8 + qq * 2 + 1] = l1;
  }
  const int lane = t & 63, w = t >> 6;
  const int m = lane & 15, quad = lane >> 4;
  const int rowA = 16 * w + m;
  bf16x8 ap[2], av[2];
  #pragma unroll
  for (int kt = 0; kt < 2; kt++) {
    ap[kt] = *(const bf16x8*)(sP + rowA * 72 + kt * 32 + quad * 8);
    av[kt] = *(const bf16x8*)(sV + rowA * 72 + kt * 32 + quad * 8);
  }
  const bf16x8* b1 = (const bf16x8*)pc1;
  const bf16x8* b2 = (const bf16x8*)pc2;
  #pragma unroll
  for (int nt = 0; nt < 4; nt++) {
    int col = nt * 16 + m;
    f32x4 c1 = {0.f, 0.f, 0.f, 0.f}, c2 = {0.f, 0.f, 0.f, 0.f};
    #pragma unroll
    for (int kt = 0; kt < 2; kt++) {
      c1 = __builtin_amdgcn_mfma_f32_16x16x32_bf16(ap[kt], b1[(kt * 4 + nt) * 64 + lane], c1, 0, 0, 0);
      c2 = __builtin_amdgcn_mfma_f32_16x16x32_bf16(av[kt], b2[(kt * 4 + nt) * 64 + lane], c2, 0, 0, 0);
    }
    float bb1 = c1b[col], bb2 = c2b[col];
    float s1 = 0.f, q1 = 0.f, s2 = 0.f, q2 = 0.f;
    #pragma unroll
    for (int reg = 0; reg < 4; reg++) {
      int gr = r0 + 16 * w + quad * 4 + reg;
      if (gr < NIMG) {
        float v1 = c1[reg] + bb1, v2 = c2[reg] + bb2;
        y1[(size_t)gr * 64 + col] = (uint16_t)f2bf(v1);
        y2[(size_t)gr * 64 + col] = (uint16_t)f2bf(v2);
        s1 += v1; q1 = fmaf(v1, v1, q1);
        s2 += v2; q2 = fmaf(v2, v2, q2);
      }
    }
    s1 += __shfl_down(s1, 32); s1 += __shfl_down(s1, 16);
    q1 += __shfl_down(q1, 32); q1 += __shfl_down(q1, 16);
    s2 += __shfl_down(s2, 32); s2 += __shfl_down(s2, 16);
    q2 += __shfl_down(q2, 32); q2 += __shfl_down(q2, 16);
    if (lane < 16) {
      float* base = sStat + (w * 4 + nt) * 64 + lane;
      base[0]  = s1;
      base[16] = q1;
      base[32] = s2;
      base[48] = q2;
    }
  }
  __syncthreads();
  {
    int kind = t >> 6, col = t & 63;
    int nt = col >> 4, mm = col & 15;
    float v = 0.f;
    #pragma unroll
    for (int ww = 0; ww < 4; ww++)
      v += sStat[(ww * 4 + nt) * 64 + kind * 16 + mm];
    unsafeAtomicAdd(&bnAcc[t], v);       // bnAcc[kind*64+col] == bnAcc[t]
  }
  if (t < 64) {
    int gr = r0 + t;
    if (gr < NIMG) {
      float l0 = attEff[256] + sAtt[t * 8] + sAtt[t * 8 + 2] + sAtt[t * 8 + 4] + sAtt[t * 8 + 6];
      float l1 = attEff[257] + sAtt[t * 8 + 1] + sAtt[t * 8 + 3] + sAtt[t * 8 + 5] + sAtt[t * 8 + 7];
      attw[gr * 2]     = 1.f / (1.f + expf(-l0));
      attw[gr * 2 + 1] = 1.f / (1.f + expf(-l1));
    }
  }
  // --- last-block BN finalize (atomic ticket, fenced) ---
  __threadfence();                       // every wave drains its own atomics
  __syncthreads();
  if (t == 0) sLast = (atomicAdd(ctr, 1) == NBLK_GA - 1) ? 1 : 0;
  __syncthreads();
  if (sLast) {
    float v = unsafeAtomicAdd(&bnAcc[t], 0.f);   // coherent L2 read
    sStat[t] = v;
    bnAcc[t] = 0.f;                              // self-clean for next scale
    __syncthreads();
    if (t < 64) {
      float nn = (float)NIMG;
      float mu1 = sStat[t] / nn;
      float var1 = sStat[64 + t] / nn - mu1 * mu1;
      float a1 = g1[t] / sqrtf(var1 + BN_EPS);
      bnpar[t] = a1; bnpar[64 + t] = be1[t] - mu1 * a1;
      float mu2 = sStat[128 + t] / nn;
      float var2 = sStat[192 + t] / nn - mu2 * mu2;
      float a2 = g2[t] / sqrtf(var2 + BN_EPS);
      bnpar[128 + t] = a2; bnpar[192 + t] = be2[t] - mu2 * a2;
    }
    if (t == 0) *ctr = 0;                        // reset ticket
  }
}

// ===== fused bundle C: scanbin(fuse s=1) + final classifier MLP (D=128) ====
__global__ void __launch_bounds__(256)
k_final_mlp(const uint16_t* __restrict__ Xh,
            const short* __restrict__ pw1, const float* __restrict__ B1,
            const short* __restrict__ pw2, const float* __restrict__ B2,
            float* __restrict__ Out,
            uint32_t* __restrict__ Hb, uint32_t* __restrict__ HFb, int callScan,
            float* __restrict__ lossesC5, int* __restrict__ gts5) {
  if (blockIdx.x < Cc) {
    scanbin_body(Hb, HFb, NIMG, callScan, lossesC5, gts5, blockIdx.x);
    return;
  }
  __shared__ __align__(16) short sXb[64 * 136];
  __shared__ __align__(16) short sH[64 * 136];
  int t = threadIdx.x, r0 = (blockIdx.x - Cc) * 64;
  for (int i = t; i < 2048; i += 256) {
    int r = i >> 5, k4 = (i & 31) * 4;
    int gr = r0 + r;
    uint2 p = (gr < NIMG) ? *(const uint2*)(Xh + (size_t)gr * 128 + k4) : make_uint2(0u, 0u);
    *(uint2*)(sXb + r * 136 + k4) = p;
  }
  __syncthreads();
  mfma_mlp_body<128>(sXb, sH, r0, NIMG, pw1, B1, pw2, B2, Out);
}

// ====== Lovász fill (+fused CE, optional fused KL, optional voxel-vote) ====
// vcnt != nullptr: label = argmax(counts row) computed inline (+self-clean).
__global__ void k_lov_fill(const float* __restrict__ logits, const int* __restrict__ lab,
                           int* __restrict__ vcnt,
                           int n, uint16_t* __restrict__ E,
                           float ceScale, float* __restrict__ lossAcc,
                           const float* __restrict__ pred3d, const int* __restrict__ idx,
                           float klScale) {
  int i = blockIdx.x * blockDim.x + threadIdx.x;
  float total = 0.f;
  if (i < n) {
    int lb;
    if (vcnt) {
      int* crow = vcnt + (size_t)i * Cc;
      int best = crow[0], arg = 0;
      crow[0] = 0;
      #pragma unroll
      for (int k = 1; k < Cc; k++) {
        int ck = crow[k]; crow[k] = 0;
        if (ck > best) { best = ck; arg = k; }   // first-max
      }
      lb = arg;
    } else {
      lb = lab[i];
    }
    const float* l = logits + (size_t)i * Cc;
    float m = l[0];
    #pragma unroll
    for (int c = 1; c < Cc; c++) m = fmaxf(m, l[c]);
    float ex[Cc]; float se = 0.f;
    #pragma unroll
    for (int c = 0; c < Cc; c++) { ex[c] = expf(l[c] - m); se += ex[c]; }
    float inv = 1.f / se;
    float lse = logf(se);
    total = -(l[lb] - m - lse) * ceScale;
    #pragma unroll
    for (int c = 0; c < Cc; c++) {
      float prob = ex[c] * inv;
      int fg = (c == lb) ? 1 : 0;
      float err = fg ? (1.f - prob) : prob;
      err = fmaxf(err, 0.f);
      uint32_t key = __float_as_uint(err) >> 17;     // < 8192
      E[(size_t)c * n + i] = (uint16_t)((key << 1) | (uint32_t)fg);
    }
    if (pred3d) {
      const float* q = pred3d + (size_t)idx[i] * Cc;
      float mq = q[0];
      #pragma unroll
      for (int c = 1; c < Cc; c++) mq = fmaxf(mq, q[c]);
      float sq = 0.f;
      #pragma unroll
      for (int c = 0; c < Cc; c++) sq += expf(q[c] - mq);
      float lsq = logf(sq);
      float kl = 0.f;
      #pragma unroll
      for (int c = 0; c < Cc; c++) {
        float lf = l[c] - m - lse;
        float pf = ex[c] * inv;
        float lq = q[c] - mq - lsq;
        kl += pf * (lf - lq);
      }
      total += kl * klScale;
    }
  }
  total = waveReduce(total);
  __shared__ float sh[4];
  int lane = threadIdx.x & 63, w = threadIdx.x >> 6;
  if (lane == 0) sh[w] = total;
  __syncthreads();
  if (threadIdx.x == 0) atomicAdd(lossAcc, sh[0] + sh[1] + sh[2] + sh[3]);
}

// ================= LDS-privatized histogram (count|fg only) ================
__global__ void __launch_bounds__(1024)
k_lov_hist2(const uint16_t* __restrict__ E, int n,
            uint32_t* __restrict__ H, uint32_t* __restrict__ HF) {
  __shared__ uint32_t lcf[NB];
  int t = threadIdx.x;
  int cls = blockIdx.x / NCH, ch = blockIdx.x - cls * NCH;
  int CHsz = (n + NCH - 1) / NCH;
  int i0 = ch * CHsz;
  int i1 = min(n, i0 + CHsz);
  for (int b = t; b < NB; b += 1024) lcf[b] = 0u;
  __syncthreads();
  const uint16_t* Ec = E + (size_t)cls * n;
  for (int i = i0 + t; i < i1; i += 1024) {
    uint32_t p = Ec[i];
    atomicAdd(&lcf[p >> 1], 0x10000u | (p & 1u));    // count hi16, fg lo16
  }
  __syncthreads();
  uint32_t* Hc  = H  + (size_t)cls * NB;
  uint32_t* HFc = HF + (size_t)cls * NB;
  for (int b = t; b < NB; b += 1024) {
    uint32_t v = lcf[b];
    if (v) {
      atomicAdd(&Hc[b], v >> 16);
      uint32_t f = v & 0xFFFFu;
      if (f) atomicAdd(&HFc[b], f);
    }
  }
}

// ================= final: fold 5 lovasz combines + output ==================
__global__ void k_final(const float* __restrict__ lossAcc,
                        const float* __restrict__ lossesC5, const int* __restrict__ gts5,
                        float* __restrict__ out) {
  const float coefs[5] = {1.0f, 0.5f, 1.0f, 0.5f, 1.0f};
  float loss = lossAcc[0];
  for (int call = 0; call < 5; call++) {
    float s = 0.f; int np = 0;
    for (int c = 0; c < Cc; c++)
      if (gts5[call * 32 + c] > 0) { s += lossesC5[call * 32 + c]; np++; }
    loss += coefs[call] * s / (float)(np > 0 ? np : 1);
  }
  out[0] = loss;
}

// ================= host-side driver =================
extern "C" void kernel_launch(void* const* d_in, const int* in_sizes, int n_in,
                              void* d_out, int out_size, void* d_ws, size_t ws_size,
                              hipStream_t stream) {
  const float* img_feat = (const float*)d_in[0];
  const float* pts_feat = (const float*)d_in[1];
  const int* coors_inv  = (const int*)d_in[2];
  const int* labels     = (const int*)d_in[3];
  const int* img_label  = (const int*)d_in[4];
  const int* p2img      = (const int*)d_in[5];
  const float* w3a = (const float*)d_in[6];
  const float* b3a = (const float*)d_in[7];
  const float* w3b = (const float*)d_in[8];
  const float* b3b = (const float*)d_in[9];
  const float* wfa = (const float*)d_in[10];
  const float* bfa = (const float*)d_in[11];
  const float* wfb = (const float*)d_in[12];
  const float* bfb = (const float*)d_in[13];
  const float* fc1w = (const float*)d_in[14];
  const float* fc1b = (const float*)d_in[15];
  const float* fc2w = (const float*)d_in[16];
  const float* fc2b = (const float*)d_in[17];
  const float* fc3w = (const float*)d_in[18];
  const float* fc3b = (const float*)d_in[19];
  const float* c1w  = (const float*)d_in[20];
  const float* c1b  = (const float*)d_in[21];
  const float* bn1g = (const float*)d_in[22];
  const float* bn1b = (const float*)d_in[23];
  const float* c2w  = (const float*)d_in[24];
  const float* c2b  = (const float*)d_in[25];
  const float* bn2g = (const float*)d_in[26];
  const float* bn2b = (const float*)d_in[27];
  const float* clw1 = (const float*)d_in[28];
  const float* clb1 = (const float*)d_in[29];
  const float* clw2 = (const float*)d_in[30];
  const float* clb2 = (const float*)d_in[31];
  (void)in_sizes; (void)n_in; (void)out_size; (void)ws_size;

  // ---- workspace layout ----
  char* ws = (char*)d_ws;
  size_t off = 0;
  auto alloc = [&](size_t bytes) { void* p = ws + off; off += (bytes + 255) & ~(size_t)255; return p; };
  uint16_t* feats = (uint16_t*)alloc((size_t)NIMG * 128 * 2);  // persistent, bf16
  float* pred3d = (float*)alloc((size_t)NV * Cc * 4);
  int*   idx    = (int*)  alloc((size_t)NIMG * 4);
  uint16_t* y1 = (uint16_t*)alloc((size_t)NIMG * Hh * 2);      // bf16
  uint16_t* y2 = (uint16_t*)alloc((size_t)NIMG * Hh * 2);
  uint16_t* E  = (uint16_t*)alloc((size_t)Cc * NV * 2);        // packed bin-key|fg
  uint32_t* H  = (uint32_t*)alloc((size_t)2 * Cc * NB * 4);
  uint32_t* HF = H + (size_t)Cc * NB;
  int*   counts   = (int*)alloc((size_t)NV * Cc * 4);          // self-cleaned by fill
  float* attw     = (float*)alloc((size_t)NIMG * 2 * 4);
  float* fusepred = (float*)alloc((size_t)NIMG * Cc * 4);
  short* pwAll = (short*)alloc(86016 * 2);                     // packed bf16 weights
  short* pw3a0 = pwAll,          * pw3a1 = pwAll + 8192;
  short* pwfa0 = pwAll + 16384,  * pwfa1 = pwAll + 24576;
  short* pw3b0 = pwAll + 32768,  * pw3b1 = pwAll + 36864;
  short* pwfb0 = pwAll + 40960,  * pwfb1 = pwAll + 45056;
  short* pcl1  = pwAll + 49152;
  short* pcl2  = pwAll + 65536;
  short* pc1w0 = pwAll + 69632,  * pc1w1 = pwAll + 73728;
  short* pc2w0 = pwAll + 77824,  * pc2w1 = pwAll + 81920;
  float* statsF  = (float*)alloc(8192);
  float* lossAcc  = statsF;             // [0]
  float* lossesC5 = statsF + 32;        // 5*32
  int*   gts5     = (int*)(statsF + 192); // 5*32 ints
  float* bnpar    = statsF + 384;       // 256 floats
  float* attEffs  = statsF + 640;       // 2*320 floats
  float* bnAcc    = statsF + 1280;      // 256 floats (BN stat atomics)
  int*   ctr      = (int*)(statsF + 1536); // last-block ticket

  // pack all weights into MFMA B-frag order + attEff (idempotent per launch)
  PackArgs pa;
  pa.d[0]  = {w3a,        pw3a0, 64, 128, 8};
  pa.d[1]  = {w3a + 8192, pw3a1, 64, 128, 8};
  pa.d[2]  = {wfa,        pwfa0, 64, 128, 8};
  pa.d[3]  = {wfa + 8192, pwfa1, 64, 128, 8};
  pa.d[4]  = {w3b,        pw3b0, 128, 20, 2};
  pa.d[5]  = {w3b + 2560, pw3b1, 128, 20, 2};
  pa.d[6]  = {wfb,        pwfb0, 128, 20, 2};
  pa.d[7]  = {wfb + 2560, pwfb1, 128, 20, 2};
  pa.d[8]  = {clw1,       pcl1, 128, 128, 8};
  pa.d[9]  = {clw2,       pcl2, 128, 20, 2};
  pa.d[10] = {c1w,        pc1w0, 64, 64, 4};
  pa.d[11] = {c1w + 4096, pc1w1, 64, 64, 4};
  pa.d[12] = {c2w,        pc2w0, 64, 64, 4};
  pa.d[13] = {c2w + 4096, pc2w1, 64, 64, 4};
  k_pack<<<128, 256, 0, stream>>>(pa, fc1w, fc1b, fc2w, fc2b, fc3w, fc3b, attEffs);
  hipMemsetAsync(statsF, 0, 8192, stream);                    // incl. bnAcc + ctr
  hipMemsetAsync(H, 0, (size_t)2 * Cc * NB * 4, stream);      // scanbin self-cleans after
  hipMemsetAsync(counts, 0, (size_t)NV * Cc * 4, stream);     // fill self-cleans after

  for (int s = 0; s < 2; s++) {
    const float* pf_s = pts_feat + (size_t)s * NV * Hh;
    const float* if_s = img_feat + (size_t)s * NIMG * Hh;
    const int*   ci_s = coors_inv + (size_t)s * NPT;
    short* pw1 = s ? pw3a1 : pw3a0;
    short* pw2 = s ? pw3b1 : pw3b0;
    short* pf1 = s ? pwfa1 : pwfa0;
    short* pf2 = s ? pwfb1 : pwfb0;
    short* pc1 = s ? pc1w1 : pc1w0;
    short* pc2 = s ? pc2w1 : pc2w0;
    // bundle A: [scanbin(call1, fuse lovasz of s=0) if s==1] + pred3d MLP + counts/idx
    if (s == 0)
      k_scale_start<false><<<NBLK_MLP + NBLK_CNT, 256, 0, stream>>>(pf_s,
          pw1, b3a, pw2, b3b, pred3d,
          ci_s, labels, counts, p2img, idx, H, HF, 0, lossesC5, gts5);
    else
      k_scale_start<true><<<Cc + NBLK_MLP + NBLK_CNT, 256, 0, stream>>>(pf_s,
          pw1, b3a + 128, pw2, b3b + Cc, pred3d,
          ci_s, labels, counts, p2img, idx, H, HF, 1, lossesC5, gts5);
    // seg_loss(pred3d, vox_lab): voxel-vote fused into fill; CE fused
    k_lov_fill<<<(NV + 255) / 256, 256, 0, stream>>>(pred3d, nullptr, counts, NV, E,
        1.0f / NV, lossAcc, nullptr, nullptr, 0.f);
    k_lov_hist2<<<Cc * NCH, 1024, 0, stream>>>(E, NV, H, HF);
    // bundle B: scanbin(call 2s, pred3d lovasz) + gather/GEMM/att + BN finalize
    k_gatt<<<Cc + NBLK_GA, 256, 0, stream>>>(pf_s, idx, if_s,
        pc1, c1b + s * 64, pc2, c2b + s * 64, attEffs + s * 320,
        y1, y2, attw, bnAcc, ctr,
        bn1g + s * 64, bn1b + s * 64, bn2g + s * 64, bn2b + s * 64, bnpar,
        H, HF, 2 * s, lossesC5, gts5);
    // fuse -> feats(bf16) + fuse_pred MLP (fused, MFMA)
    k_fusemlp<<<NBLK_GA, 256, 0, stream>>>(y1, y2, attw, bnpar, feats, s * 64,
        pf1, bfa + s * 128, pf2, bfb + s * Cc, fusepred);
    // seg_loss(fuse_pred)*0.5: CE fused + KL fused
    k_lov_fill<<<(NIMG + 255) / 256, 256, 0, stream>>>(fusepred, img_label, nullptr, NIMG, E,
        0.5f / NIMG, lossAcc, pred3d, idx, 0.025f / ((float)NIMG * Cc));
    k_lov_hist2<<<Cc * NCH, 1024, 0, stream>>>(E, NIMG, H, HF);
    // scanbin(call 2s+1) deferred: rides in next bundle (A of s=1, or C)
  }
  // bundle C: scanbin(call3, fuse lovasz of s=1) + final classifier MLP
  k_final_mlp<<<Cc + NBLK_GA, 256, 0, stream>>>(feats,
      pcl1, clb1, pcl2, clb2, fusepred, H, HF, 3, lossesC5, gts5);
  k_lov_fill<<<(NIMG + 255) / 256, 256, 0, stream>>>(fusepred, img_label, nullptr, NIMG, E,
      1.0f / NIMG, lossAcc, nullptr, nullptr, 0.f);
  k_lov_hist2<<<Cc * NCH, 1024, 0, stream>>>(E, NIMG, H, HF);
  k_scanbin5<<<Cc, 256, 0, stream>>>(H, HF, NIMG, 4, lossesC5, gts5);
  k_final<<<1, 1, 0, stream>>>(lossAcc, lossesC5, gts5, (float*)d_out);
}

// Round 2
// 396.100 us; speedup vs baseline: 1.4456x; 1.4456x over previous
//
#include <hip/hip_runtime.h>
#include <stdint.h>

// ---- problem constants (from setup_inputs) ----
static constexpr int NV   = 80000;    // voxels per scale
static constexpr int NPT  = 240000;   // points N
static constexpr int NIMG = 60000;    // B*M image-projected points
static constexpr int Hh   = 64;
static constexpr int Cc   = 20;
static constexpr int NPp  = 120000;   // N per batch
static constexpr int Mm   = 30000;
static constexpr int NB     = 8192;   // error-histogram bins (top-15 float bits)
static constexpr int NCH    = 16;     // chunks per class in hist kernel
static constexpr int NBLK_GA  = (NIMG + 63) / 64;   // 938 gemm_att blocks
static constexpr int NBLK_MLP = NV / 64;            // 1250 pred3d-mlp blocks
static constexpr int NBLK_CNT = (NPT + 255) / 256;  // 938 counts/idx blocks
#define BN_EPS 1e-5f

using bf16x8 = __attribute__((ext_vector_type(8))) short;
using f32x4  = __attribute__((ext_vector_type(4))) float;

// ================= small helpers =================
__device__ __forceinline__ float waveReduce(float v) {
  #pragma unroll
  for (int o = 32; o > 0; o >>= 1) v += __shfl_down(v, o);
  return v;
}
__device__ __forceinline__ short f2bf(float f) {   // RNE fp32 -> bf16
  uint32_t u = __float_as_uint(f);
  return (short)((u + 0x7FFFu + ((u >> 16) & 1u)) >> 16);
}
__device__ __forceinline__ float bf2f(uint32_t h) { return __uint_as_float(h << 16); }
__device__ __forceinline__ uint32_t pk2(float a, float b) {
  return ((uint32_t)(uint16_t)f2bf(a)) | ((uint32_t)(uint16_t)f2bf(b) << 16);
}

// ================= weight pre-pack into MFMA B-frag order (+attEff) ========
struct PackDesc { const float* src; short* dst; int K, Nr, nt; };
struct PackArgs { PackDesc d[14]; };

__global__ void k_pack(PackArgs pa,
                       const float* __restrict__ fc1w, const float* __restrict__ fc1b,
                       const float* __restrict__ fc2w, const float* __restrict__ fc2b,
                       const float* __restrict__ fc3w, const float* __restrict__ fc3b,
                       float* __restrict__ attEffs) {
  int stride = gridDim.x * blockDim.x;
  for (int di = 0; di < 14; di++) {
    const float* src = pa.d[di].src;
    short* dst = pa.d[di].dst;
    int K = pa.d[di].K, Nr = pa.d[di].Nr, ntiles = pa.d[di].nt;
    int total = (K / 32) * ntiles * 512;
    for (int idx = blockIdx.x * blockDim.x + threadIdx.x; idx < total; idx += stride) {
      int j = idx & 7, lane = (idx >> 3) & 63, tile = idx >> 9;
      int nt = tile % ntiles, kt = tile / ntiles;
      int k = kt * 32 + (lane >> 4) * 8 + j;
      int n = nt * 16 + (lane & 15);
      float v = (n < Nr) ? src[(size_t)k * Nr + n] : 0.f;
      dst[idx] = f2bf(v);
    }
  }
  if (blockIdx.x < 2 && threadIdx.x < 64) {
    int s = blockIdx.x, t = threadIdx.x;
    const float* f1w = fc1w + s * 64 * 16; const float* f1b = fc1b + s * 16;
    const float* f2w = fc2w + s * 64 * 16; const float* f2b = fc2b + s * 16;
    const float* f3w = fc3w + s * 64;      const float* f3b = fc3b + s * 2;
    float* aE = attEffs + s * 320;
    float p0 = 0.f, p1 = 0.f, v0 = 0.f, v1 = 0.f;
    #pragma unroll
    for (int j = 0; j < 16; j++) {
      p0 = fmaf(f1w[t * 16 + j], f3w[j * 2], p0);
      p1 = fmaf(f1w[t * 16 + j], f3w[j * 2 + 1], p1);
      v0 = fmaf(f2w[t * 16 + j], f3w[(16 + j) * 2], v0);
      v1 = fmaf(f2w[t * 16 + j], f3w[(16 + j) * 2 + 1], v1);
    }
    aE[t * 2] = p0; aE[t * 2 + 1] = p1;
    aE[128 + t * 2] = v0; aE[128 + t * 2 + 1] = v1;
    if (t == 0) {
      float b0 = f3b[0], b1 = f3b[1];
      for (int j = 0; j < 16; j++) {
        b0 += f1b[j] * f3w[j * 2] + f2b[j] * f3w[(16 + j) * 2];
        b1 += f1b[j] * f3w[j * 2 + 1] + f2b[j] * f3w[(16 + j) * 2 + 1];
      }
      aE[256] = b0; aE[257] = b1;
    }
  }
}

// ====== Lovász scan+bin body: register-resident, wave-scan (self-cleaning) ==
__device__ void scanbin_body(uint32_t* __restrict__ Hb, uint32_t* __restrict__ HFb,
                             int n, int call, float* __restrict__ lossesC5,
                             int* __restrict__ gts5, int cls) {
  __shared__ int sWC[4], sWF[4];
  __shared__ float sRedF[4];
  int t = threadIdx.x;
  int lane = t & 63, w = t >> 6;
  uint32_t* Hc  = Hb  + (size_t)cls * NB;
  uint32_t* HFc = HFb + (size_t)cls * NB;
  int locC = 0, locF = 0;
  #pragma unroll
  for (int i = 0; i < 8; i++) {
    uint4 cv = *(const uint4*)(Hc  + t * 32 + i * 4);
    uint4 fv = *(const uint4*)(HFc + t * 32 + i * 4);
    locC += (int)(cv.x + cv.y + cv.z + cv.w);
    locF += (int)(fv.x + fv.y + fv.z + fv.w);
  }
  int sc = locC, sf = locF;
  #pragma unroll
  for (int o = 1; o < 64; o <<= 1) {
    int a = __shfl_up(sc, o);
    int b = __shfl_up(sf, o);
    if (lane >= o) { sc += a; sf += b; }
  }
  if (lane == 63) { sWC[w] = sc; sWF[w] = sf; }
  __syncthreads();
  int offC = 0, offF = 0, Ftot = 0;
  #pragma unroll
  for (int ww = 0; ww < 4; ww++) {
    int fc = sWF[ww];
    Ftot += fc;
    if (ww < w) { offC += sWC[ww]; offF += fc; }
  }
  int runC = offC + sc - locC;    // exclusive prefix (ascending bins)
  int runF = offF + sf - locF;
  float gts = (float)Ftot;
  float contrib = 0.f;
  const uint4 z = make_uint4(0u, 0u, 0u, 0u);
  #pragma unroll
  for (int i = 0; i < 8; i++) {
    uint4 cv = *(const uint4*)(Hc  + t * 32 + i * 4);
    uint4 fv = *(const uint4*)(HFc + t * 32 + i * 4);
    *(uint4*)(Hc  + t * 32 + i * 4) = z;                 // self-clean
    *(uint4*)(HFc + t * 32 + i * 4) = z;
    uint32_t ca[4] = {cv.x, cv.y, cv.z, cv.w};
    uint32_t fa[4] = {fv.x, fv.y, fv.z, fv.w};
    #pragma unroll
    for (int j = 0; j < 4; j++) {
      int cnt = (int)ca[j], fgc = (int)fa[j];
      runC += cnt; runF += fgc;                          // ascending inclusive
      if (cnt > 0 && Ftot > 0) {
        float r0 = (float)(n - runC);                    // elements with larger err
        float F0 = (float)(Ftot - runF);
        float r1 = r0 + (float)cnt;
        float F1 = F0 + (float)fgc;
        float emean = __uint_as_float((uint32_t)(t * 32 + i * 4 + j) << 17);
        contrib += emean * (r1 / (gts + r1 - F1) - r0 / (gts + r0 - F0));
      }
    }
  }
  contrib = waveReduce(contrib);
  if (lane == 0) sRedF[w] = contrib;
  __syncthreads();
  if (t == 0) {
    lossesC5[call * 32 + cls] = (Ftot > 0) ? (sRedF[0] + sRedF[1] + sRedF[2] + sRedF[3]) : 0.f;
    gts5[call * 32 + cls] = Ftot;
  }
}

__global__ void __launch_bounds__(256)
k_scanbin5(uint32_t* __restrict__ Hb, uint32_t* __restrict__ HFb, int n, int call,
           float* __restrict__ lossesC5, int* __restrict__ gts5) {
  scanbin_body(Hb, HFb, n, call, lossesC5, gts5, blockIdx.x);
}

// ================= MFMA MLP body: relu(X@W1+b1)@W2+b2 ====================
template<int D>
__device__ __forceinline__ void mfma_mlp_body(const short* sXb, short* sH,
    int r0, int rows,
    const short* __restrict__ pw1, const float* __restrict__ B1,
    const short* __restrict__ pw2, const float* __restrict__ B2,
    float* __restrict__ Out) {
  constexpr int LDB = D + 8;
  constexpr int KT1 = D / 32;
  const int t = threadIdx.x;
  const int lane = t & 63, w = t >> 6;
  const int m = lane & 15, quad = lane >> 4;
  const int rowA = 16 * w + m;
  bf16x8 a1[KT1];
  #pragma unroll
  for (int kt = 0; kt < KT1; kt++)
    a1[kt] = *(const bf16x8*)(sXb + rowA * LDB + kt * 32 + quad * 8);
  const bf16x8* b1 = (const bf16x8*)pw1;
  #pragma unroll
  for (int nt = 0; nt < 8; nt++) {
    f32x4 c = {0.f, 0.f, 0.f, 0.f};
    #pragma unroll
    for (int kt = 0; kt < KT1; kt++)
      c = __builtin_amdgcn_mfma_f32_16x16x32_bf16(a1[kt], b1[(kt * 8 + nt) * 64 + lane], c, 0, 0, 0);
    int col = nt * 16 + m;
    float bc = B1[col];
    #pragma unroll
    for (int reg = 0; reg < 4; reg++)
      sH[(16 * w + quad * 4 + reg) * 136 + col] = f2bf(fmaxf(c[reg] + bc, 0.f));
  }
  __syncthreads();
  bf16x8 a2[4];
  #pragma unroll
  for (int kt = 0; kt < 4; kt++)
    a2[kt] = *(const bf16x8*)(sH + rowA * 136 + kt * 32 + quad * 8);
  const bf16x8* b2 = (const bf16x8*)pw2;
  #pragma unroll
  for (int nt = 0; nt < 2; nt++) {
    f32x4 c = {0.f, 0.f, 0.f, 0.f};
    #pragma unroll
    for (int kt = 0; kt < 4; kt++)
      c = __builtin_amdgcn_mfma_f32_16x16x32_bf16(a2[kt], b2[(kt * 2 + nt) * 64 + lane], c, 0, 0, 0);
    int col = nt * 16 + m;
    if (col < Cc) {
      float bc = B2[col];
      #pragma unroll
      for (int reg = 0; reg < 4; reg++) {
        int gr = r0 + 16 * w + quad * 4 + reg;
        if (gr < rows) Out[(size_t)gr * Cc + col] = c[reg] + bc;
      }
    }
  }
}

// ========== fused bundle A: [scanbin(prev)] + pred3d MLP + counts/idx ======
template<bool WITH_SCAN>
__global__ void __launch_bounds__(256)
k_scale_start(const float* __restrict__ X,
              const short* __restrict__ pw1, const float* __restrict__ B1,
              const short* __restrict__ pw2, const float* __restrict__ B2,
              float* __restrict__ Out,
              const int* __restrict__ ci, const int* __restrict__ labels,
              int* __restrict__ counts, const int* __restrict__ p2img,
              int* __restrict__ idx,
              uint32_t* __restrict__ Hb, uint32_t* __restrict__ HFb, int callScan,
              float* __restrict__ lossesC5, int* __restrict__ gts5) {
  int bid = blockIdx.x;
  if (WITH_SCAN) {
    if (bid < Cc) { scanbin_body(Hb, HFb, NIMG, callScan, lossesC5, gts5, bid); return; }
    bid -= Cc;
  }
  if (bid < NBLK_MLP) {
    __shared__ __align__(16) short sXb[64 * 72];
    __shared__ __align__(16) short sH[64 * 136];
    int t = threadIdx.x, r0 = bid * 64;
    for (int i = t; i < 1024; i += 256) {     // NV % 64 == 0: no row guard
      int r = i >> 4, k4 = (i & 15) * 4;
      float4 v = *(const float4*)(X + (size_t)(r0 + r) * 64 + k4);
      uint2 p; p.x = pk2(v.x, v.y); p.y = pk2(v.z, v.w);
      *(uint2*)(sXb + r * 72 + k4) = p;
    }
    __syncthreads();
    mfma_mlp_body<64>(sXb, sH, r0, NV, pw1, B1, pw2, B2, Out);
  } else {
    int i = (bid - NBLK_MLP) * 256 + threadIdx.x;
    if (i < NIMG) {
      int b = (i >= Mm) ? 1 : 0;               // B=2, contiguous batch blocks
      idx[i] = ci[b * NPp + p2img[i]];
    }
    if (i < NPT) atomicAdd(&counts[(size_t)ci[i] * Cc + labels[i]], 1);
  }
}

// ================= fused BN+att fuse -> feats(bf16) + fuse-MLP (MFMA) ======
__global__ void __launch_bounds__(256)
k_fusemlp(const uint16_t* __restrict__ y1, const uint16_t* __restrict__ y2,
          const float* __restrict__ attw, const float* __restrict__ bnpar,
          uint16_t* __restrict__ feats, int s64,
          const short* __restrict__ pw1, const float* __restrict__ B1,
          const short* __restrict__ pw2, const float* __restrict__ B2,
          float* __restrict__ Out) {
  __shared__ __align__(16) short sXb[64 * 72];
  __shared__ __align__(16) short sH[64 * 136];
  int t = threadIdx.x, r0 = blockIdx.x * 64;
  for (int i = t; i < 1024; i += 256) {
    int r = i >> 4, q = i & 15;
    int gr = r0 + r;
    uint2 zp = make_uint2(0u, 0u);
    if (gr < NIMG) {
      float4 a1 = *(const float4*)(bnpar + q * 4);
      float4 c1 = *(const float4*)(bnpar + 64 + q * 4);
      float4 a2 = *(const float4*)(bnpar + 128 + q * 4);
      float4 c2 = *(const float4*)(bnpar + 192 + q * 4);
      uint2 u1 = *(const uint2*)(y1 + (size_t)gr * 64 + q * 4);
      uint2 u2 = *(const uint2*)(y2 + (size_t)gr * 64 + q * 4);
      float w0 = attw[gr * 2], w1 = attw[gr * 2 + 1];
      float zx = fmaxf(fmaf(bf2f(u1.x & 0xffff), a1.x, c1.x), 0.f) * w0
               + fmaxf(fmaf(bf2f(u2.x & 0xffff), a2.x, c2.x), 0.f) * w1;
      float zy = fmaxf(fmaf(bf2f(u1.x >> 16),   a1.y, c1.y), 0.f) * w0
               + fmaxf(fmaf(bf2f(u2.x >> 16),   a2.y, c2.y), 0.f) * w1;
      float zz = fmaxf(fmaf(bf2f(u1.y & 0xffff), a1.z, c1.z), 0.f) * w0
               + fmaxf(fmaf(bf2f(u2.y & 0xffff), a2.z, c2.z), 0.f) * w1;
      float zw = fmaxf(fmaf(bf2f(u1.y >> 16),   a1.w, c1.w), 0.f) * w0
               + fmaxf(fmaf(bf2f(u2.y >> 16),   a2.w, c2.w), 0.f) * w1;
      zp.x = pk2(zx, zy); zp.y = pk2(zz, zw);
      *(uint2*)(feats + (size_t)gr * 128 + s64 + q * 4) = zp;
    }
    *(uint2*)(sXb + r * 72 + q * 4) = zp;
  }
  __syncthreads();
  mfma_mlp_body<64>(sXb, sH, r0, NIMG, pw1, B1, pw2, B2, Out);
}

// == fused bundle B: scanbin(pred3d) + gather/GEMM/att + atomic-free stats ==
__global__ void __launch_bounds__(256)
k_gatt(const float* __restrict__ pts, const int* __restrict__ idx,
       const float* __restrict__ img,
       const short* __restrict__ pc1, const float* __restrict__ c1b,
       const short* __restrict__ pc2, const float* __restrict__ c2b,
       const float* __restrict__ attEff,
       uint16_t* __restrict__ y1, uint16_t* __restrict__ y2,
       float* __restrict__ attw, float* __restrict__ partials,
       uint32_t* __restrict__ Hb, uint32_t* __restrict__ HFb, int callScan,
       float* __restrict__ lossesC5, int* __restrict__ gts5) {
  if (blockIdx.x < Cc) {
    scanbin_body(Hb, HFb, NV, callScan, lossesC5, gts5, blockIdx.x);
    return;
  }
  __shared__ __align__(16) short sP[64 * 72], sV[64 * 72];
  __shared__ float sAtt[64 * 8];
  __shared__ float sStat[1024];        // [w][nt][kind][m]
  int t = threadIdx.x;
  int bb = blockIdx.x - Cc;
  int r0 = bb * 64;
  for (int i = t; i < 1024; i += 256) {
    int r = i >> 4, q = i & 15;
    int gr = r0 + r;
    float4 vp = make_float4(0.f, 0.f, 0.f, 0.f), vv = vp;
    if (gr < NIMG) {
      vp = *(const float4*)(pts + (size_t)idx[gr] * 64 + q * 4);
      vv = *(const float4*)(img + (size_t)gr * 64 + q * 4);
    }
    uint2 pp, qv;
    pp.x = pk2(vp.x, vp.y); pp.y = pk2(vp.z, vp.w);
    qv.x = pk2(vv.x, vv.y); qv.y = pk2(vv.z, vv.w);
    *(uint2*)(sP + r * 72 + q * 4) = pp;
    *(uint2*)(sV + r * 72 + q * 4) = qv;
  }
  __syncthreads();
  {
    int r = t & 63, qq = t >> 6;
    const float* aP = attEff;
    const float* aV = attEff + 128;
    float l0 = 0.f, l1 = 0.f;
    for (int k = qq * 16; k < qq * 16 + 16; k += 4) {
      uint2 up = *(const uint2*)(sP + r * 72 + k);
      uint2 uv = *(const uint2*)(sV + r * 72 + k);
      float p0 = bf2f(up.x & 0xffff), p1 = bf2f(up.x >> 16);
      float p2 = bf2f(up.y & 0xffff), p3 = bf2f(up.y >> 16);
      float v0 = bf2f(uv.x & 0xffff), v1 = bf2f(uv.x >> 16);
      float v2 = bf2f(uv.y & 0xffff), v3 = bf2f(uv.y >> 16);
      float4 wa = *(const float4*)(aP + 2 * k);
      float4 wb = *(const float4*)(aP + 2 * k + 4);
      l0 += p0 * wa.x + p1 * wa.z + p2 * wb.x + p3 * wb.z;
      l1 += p0 * wa.y + p1 * wa.w + p2 * wb.y + p3 * wb.w;
      float4 ua = *(const float4*)(aV + 2 * k);
      float4 ub = *(const float4*)(aV + 2 * k + 4);
      l0 += v0 * ua.x + v1 * ua.z + v2 * ub.x + v3 * ub.z;
      l1 += v0 * ua.y + v1 * ua.w + v2 * ub.y + v3 * ub.w;
    }
    sAtt[r * 8 + qq * 2] = l0;
    sAtt[r * 8 + qq * 2 + 1] = l1;
  }
  const int lane = t & 63, w = t >> 6;
  const int m = lane & 15, quad = lane >> 4;
  const int rowA = 16 * w + m;
  bf16x8 ap[2], av[2];
  #pragma unroll
  for (int kt = 0; kt < 2; kt++) {
    ap[kt] = *(const bf16x8*)(sP + rowA * 72 + kt * 32 + quad * 8);
    av[kt] = *(const bf16x8*)(sV + rowA * 72 + kt * 32 + quad * 8);
  }
  const bf16x8* b1 = (const bf16x8*)pc1;
  const bf16x8* b2 = (const bf16x8*)pc2;
  #pragma unroll
  for (int nt = 0; nt < 4; nt++) {
    int col = nt * 16 + m;
    f32x4 c1 = {0.f, 0.f, 0.f, 0.f}, c2 = {0.f, 0.f, 0.f, 0.f};
    #pragma unroll
    for (int kt = 0; kt < 2; kt++) {
      c1 = __builtin_amdgcn_mfma_f32_16x16x32_bf16(ap[kt], b1[(kt * 4 + nt) * 64 + lane], c1, 0, 0, 0);
      c2 = __builtin_amdgcn_mfma_f32_16x16x32_bf16(av[kt], b2[(kt * 4 + nt) * 64 + lane], c2, 0, 0, 0);
    }
    float bb1 = c1b[col], bb2 = c2b[col];
    float s1 = 0.f, q1 = 0.f, s2 = 0.f, q2 = 0.f;
    #pragma unroll
    for (int reg = 0; reg < 4; reg++) {
      int gr = r0 + 16 * w + quad * 4 + reg;
      if (gr < NIMG) {
        float v1 = c1[reg] + bb1, v2 = c2[reg] + bb2;
        y1[(size_t)gr * 64 + col] = (uint16_t)f2bf(v1);
        y2[(size_t)gr * 64 + col] = (uint16_t)f2bf(v2);
        s1 += v1; q1 = fmaf(v1, v1, q1);
        s2 += v2; q2 = fmaf(v2, v2, q2);
      }
    }
    s1 += __shfl_down(s1, 32); s1 += __shfl_down(s1, 16);
    q1 += __shfl_down(q1, 32); q1 += __shfl_down(q1, 16);
    s2 += __shfl_down(s2, 32); s2 += __shfl_down(s2, 16);
    q2 += __shfl_down(q2, 32); q2 += __shfl_down(q2, 16);
    if (lane < 16) {
      float* base = sStat + (w * 4 + nt) * 64 + lane;
      base[0]  = s1;
      base[16] = q1;
      base[32] = s2;
      base[48] = q2;
    }
  }
  __syncthreads();
  {
    int kind = t >> 6, col = t & 63;
    int nt = col >> 4, mm = col & 15;
    float v = 0.f;
    #pragma unroll
    for (int ww = 0; ww < 4; ww++)
      v += sStat[(ww * 4 + nt) * 64 + kind * 16 + mm];
    partials[(size_t)bb * 256 + kind * 64 + col] = v;
  }
  if (t < 64) {
    int gr = r0 + t;
    if (gr < NIMG) {
      float l0 = attEff[256] + sAtt[t * 8] + sAtt[t * 8 + 2] + sAtt[t * 8 + 4] + sAtt[t * 8 + 6];
      float l1 = attEff[257] + sAtt[t * 8 + 1] + sAtt[t * 8 + 3] + sAtt[t * 8 + 5] + sAtt[t * 8 + 7];
      attw[gr * 2]     = 1.f / (1.f + expf(-l0));
      attw[gr * 2 + 1] = 1.f / (1.f + expf(-l1));
    }
  }
}

// ====== BN partial reduction, stage 1: 64 blocks over 938 rows =============
__global__ void __launch_bounds__(256)
k_colred(const float* __restrict__ partials, int nblk, float* __restrict__ red64) {
  int t = threadIdx.x, j = blockIdx.x;       // 64 blocks
  float v = 0.f;
  for (int b = j; b < nblk; b += 64) v += partials[(size_t)b * 256 + t];
  red64[j * 256 + t] = v;
}

// ====== BN finalize, stage 2: reduce 64x256 + compute bnpar ================
__global__ void __launch_bounds__(1024)
k_colfinal(const float* __restrict__ red64,
           const float* __restrict__ g1, const float* __restrict__ be1,
           const float* __restrict__ g2, const float* __restrict__ be2,
           float* __restrict__ bnpar) {
  __shared__ float red[1024];
  int t = threadIdx.x;
  int slot = t & 255, part = t >> 8;          // 4 partitions over the 64 rows
  float v = 0.f;
  for (int b = part; b < 64; b += 4) v += red64[b * 256 + slot];
  red[part * 256 + slot] = v;
  __syncthreads();
  if (t < 256) red[t] = red[t] + red[256 + t] + red[512 + t] + red[768 + t];
  __syncthreads();
  if (t < 64) {
    float n = (float)NIMG;
    float mu1 = red[t] / n;
    float var1 = red[64 + t] / n - mu1 * mu1;
    float a1 = g1[t] / sqrtf(var1 + BN_EPS);
    bnpar[t] = a1; bnpar[64 + t] = be1[t] - mu1 * a1;
    float mu2 = red[128 + t] / n;
    float var2 = red[192 + t] / n - mu2 * mu2;
    float a2 = g2[t] / sqrtf(var2 + BN_EPS);
    bnpar[128 + t] = a2; bnpar[192 + t] = be2[t] - mu2 * a2;
  }
}

// ===== fused bundle C: scanbin(fuse s=1) + final classifier MLP (D=128) ====
__global__ void __launch_bounds__(256)
k_final_mlp(const uint16_t* __restrict__ Xh,
            const short* __restrict__ pw1, const float* __restrict__ B1,
            const short* __restrict__ pw2, const float* __restrict__ B2,
            float* __restrict__ Out,
            uint32_t* __restrict__ Hb, uint32_t* __restrict__ HFb, int callScan,
            float* __restrict__ lossesC5, int* __restrict__ gts5) {
  if (blockIdx.x < Cc) {
    scanbin_body(Hb, HFb, NIMG, callScan, lossesC5, gts5, blockIdx.x);
    return;
  }
  __shared__ __align__(16) short sXb[64 * 136];
  __shared__ __align__(16) short sH[64 * 136];
  int t = threadIdx.x, r0 = (blockIdx.x - Cc) * 64;
  for (int i = t; i < 2048; i += 256) {
    int r = i >> 5, k4 = (i & 31) * 4;
    int gr = r0 + r;
    uint2 p = (gr < NIMG) ? *(const uint2*)(Xh + (size_t)gr * 128 + k4) : make_uint2(0u, 0u);
    *(uint2*)(sXb + r * 136 + k4) = p;
  }
  __syncthreads();
  mfma_mlp_body<128>(sXb, sH, r0, NIMG, pw1, B1, pw2, B2, Out);
}

// ====== Lovász fill (+fused CE, optional fused KL, optional voxel-vote) ====
// vcnt != nullptr: label = argmax(counts row) computed inline (+self-clean).
__global__ void k_lov_fill(const float* __restrict__ logits, const int* __restrict__ lab,
                           int* __restrict__ vcnt,
                           int n, uint16_t* __restrict__ E,
                           float ceScale, float* __restrict__ lossAcc,
                           const float* __restrict__ pred3d, const int* __restrict__ idx,
                           float klScale) {
  int i = blockIdx.x * blockDim.x + threadIdx.x;
  float total = 0.f;
  if (i < n) {
    int lb;
    if (vcnt) {
      int* crow = vcnt + (size_t)i * Cc;
      int best = crow[0], arg = 0;
      crow[0] = 0;
      #pragma unroll
      for (int k = 1; k < Cc; k++) {
        int ck = crow[k]; crow[k] = 0;
        if (ck > best) { best = ck; arg = k; }   // first-max
      }
      lb = arg;
    } else {
      lb = lab[i];
    }
    const float* l = logits + (size_t)i * Cc;
    float m = l[0];
    #pragma unroll
    for (int c = 1; c < Cc; c++) m = fmaxf(m, l[c]);
    float ex[Cc]; float se = 0.f;
    #pragma unroll
    for (int c = 0; c < Cc; c++) { ex[c] = expf(l[c] - m); se += ex[c]; }
    float inv = 1.f / se;
    float lse = logf(se);
    total = -(l[lb] - m - lse) * ceScale;
    #pragma unroll
    for (int c = 0; c < Cc; c++) {
      float prob = ex[c] * inv;
      int fg = (c == lb) ? 1 : 0;
      float err = fg ? (1.f - prob) : prob;
      err = fmaxf(err, 0.f);
      uint32_t key = __float_as_uint(err) >> 17;     // < 8192
      E[(size_t)c * n + i] = (uint16_t)((key << 1) | (uint32_t)fg);
    }
    if (pred3d) {
      const float* q = pred3d + (size_t)idx[i] * Cc;
      float mq = q[0];
      #pragma unroll
      for (int c = 1; c < Cc; c++) mq = fmaxf(mq, q[c]);
      float sq = 0.f;
      #pragma unroll
      for (int c = 0; c < Cc; c++) sq += expf(q[c] - mq);
      float lsq = logf(sq);
      float kl = 0.f;
      #pragma unroll
      for (int c = 0; c < Cc; c++) {
        float lf = l[c] - m - lse;
        float pf = ex[c] * inv;
        float lq = q[c] - mq - lsq;
        kl += pf * (lf - lq);
      }
      total += kl * klScale;
    }
  }
  total = waveReduce(total);
  __shared__ float sh[4];
  int lane = threadIdx.x & 63, w = threadIdx.x >> 6;
  if (lane == 0) sh[w] = total;
  __syncthreads();
  if (threadIdx.x == 0) atomicAdd(lossAcc, sh[0] + sh[1] + sh[2] + sh[3]);
}

// ================= LDS-privatized histogram (count|fg only) ================
__global__ void __launch_bounds__(1024)
k_lov_hist2(const uint16_t* __restrict__ E, int n,
            uint32_t* __restrict__ H, uint32_t* __restrict__ HF) {
  __shared__ uint32_t lcf[NB];
  int t = threadIdx.x;
  int cls = blockIdx.x / NCH, ch = blockIdx.x - cls * NCH;
  int CHsz = (n + NCH - 1) / NCH;
  int i0 = ch * CHsz;
  int i1 = min(n, i0 + CHsz);
  for (int b = t; b < NB; b += 1024) lcf[b] = 0u;
  __syncthreads();
  const uint16_t* Ec = E + (size_t)cls * n;
  for (int i = i0 + t; i < i1; i += 1024) {
    uint32_t p = Ec[i];
    atomicAdd(&lcf[p >> 1], 0x10000u | (p & 1u));    // count hi16, fg lo16
  }
  __syncthreads();
  uint32_t* Hc  = H  + (size_t)cls * NB;
  uint32_t* HFc = HF + (size_t)cls * NB;
  for (int b = t; b < NB; b += 1024) {
    uint32_t v = lcf[b];
    if (v) {
      atomicAdd(&Hc[b], v >> 16);
      uint32_t f = v & 0xFFFFu;
      if (f) atomicAdd(&HFc[b], f);
    }
  }
}

// ================= final: fold 5 lovasz combines + output ==================
__global__ void k_final(const float* __restrict__ lossAcc,
                        const float* __restrict__ lossesC5, const int* __restrict__ gts5,
                        float* __restrict__ out) {
  const float coefs[5] = {1.0f, 0.5f, 1.0f, 0.5f, 1.0f};
  float loss = lossAcc[0];
  for (int call = 0; call < 5; call++) {
    float s = 0.f; int np = 0;
    for (int c = 0; c < Cc; c++)
      if (gts5[call * 32 + c] > 0) { s += lossesC5[call * 32 + c]; np++; }
    loss += coefs[call] * s / (float)(np > 0 ? np : 1);
  }
  out[0] = loss;
}

// ================= host-side driver =================
extern "C" void kernel_launch(void* const* d_in, const int* in_sizes, int n_in,
                              void* d_out, int out_size, void* d_ws, size_t ws_size,
                              hipStream_t stream) {
  const float* img_feat = (const float*)d_in[0];
  const float* pts_feat = (const float*)d_in[1];
  const int* coors_inv  = (const int*)d_in[2];
  const int* labels     = (const int*)d_in[3];
  const int* img_label  = (const int*)d_in[4];
  const int* p2img      = (const int*)d_in[5];
  const float* w3a = (const float*)d_in[6];
  const float* b3a = (const float*)d_in[7];
  const float* w3b = (const float*)d_in[8];
  const float* b3b = (const float*)d_in[9];
  const float* wfa = (const float*)d_in[10];
  const float* bfa = (const float*)d_in[11];
  const float* wfb = (const float*)d_in[12];
  const float* bfb = (const float*)d_in[13];
  const float* fc1w = (const float*)d_in[14];
  const float* fc1b = (const float*)d_in[15];
  const float* fc2w = (const float*)d_in[16];
  const float* fc2b = (const float*)d_in[17];
  const float* fc3w = (const float*)d_in[18];
  const float* fc3b = (const float*)d_in[19];
  const float* c1w  = (const float*)d_in[20];
  const float* c1b  = (const float*)d_in[21];
  const float* bn1g = (const float*)d_in[22];
  const float* bn1b = (const float*)d_in[23];
  const float* c2w  = (const float*)d_in[24];
  const float* c2b  = (const float*)d_in[25];
  const float* bn2g = (const float*)d_in[26];
  const float* bn2b = (const float*)d_in[27];
  const float* clw1 = (const float*)d_in[28];
  const float* clb1 = (const float*)d_in[29];
  const float* clw2 = (const float*)d_in[30];
  const float* clb2 = (const float*)d_in[31];
  (void)in_sizes; (void)n_in; (void)out_size; (void)ws_size;

  // ---- workspace layout ----
  char* ws = (char*)d_ws;
  size_t off = 0;
  auto alloc = [&](size_t bytes) { void* p = ws + off; off += (bytes + 255) & ~(size_t)255; return p; };
  uint16_t* feats = (uint16_t*)alloc((size_t)NIMG * 128 * 2);  // persistent, bf16
  float* pred3d = (float*)alloc((size_t)NV * Cc * 4);
  int*   idx    = (int*)  alloc((size_t)NIMG * 4);
  uint16_t* y1 = (uint16_t*)alloc((size_t)NIMG * Hh * 2);      // bf16
  uint16_t* y2 = (uint16_t*)alloc((size_t)NIMG * Hh * 2);
  uint16_t* E  = (uint16_t*)alloc((size_t)Cc * NV * 2);        // packed bin-key|fg
  uint32_t* H  = (uint32_t*)alloc((size_t)2 * Cc * NB * 4);
  uint32_t* HF = H + (size_t)Cc * NB;
  float* partials = (float*)alloc((size_t)NBLK_GA * 256 * 4);  // BN stat partials
  float* red64    = (float*)alloc(64 * 256 * 4);               // stage-1 reduction
  int*   counts   = (int*)alloc((size_t)NV * Cc * 4);          // self-cleaned by fill
  float* attw     = (float*)alloc((size_t)NIMG * 2 * 4);
  float* fusepred = (float*)alloc((size_t)NIMG * Cc * 4);
  short* pwAll = (short*)alloc(86016 * 2);                     // packed bf16 weights
  short* pw3a0 = pwAll,          * pw3a1 = pwAll + 8192;
  short* pwfa0 = pwAll + 16384,  * pwfa1 = pwAll + 24576;
  short* pw3b0 = pwAll + 32768,  * pw3b1 = pwAll + 36864;
  short* pwfb0 = pwAll + 40960,  * pwfb1 = pwAll + 45056;
  short* pcl1  = pwAll + 49152;
  short* pcl2  = pwAll + 65536;
  short* pc1w0 = pwAll + 69632,  * pc1w1 = pwAll + 73728;
  short* pc2w0 = pwAll + 77824,  * pc2w1 = pwAll + 81920;
  float* statsF  = (float*)alloc(8192);
  float* lossAcc  = statsF;             // [0]
  float* lossesC5 = statsF + 32;        // 5*32
  int*   gts5     = (int*)(statsF + 192); // 5*32 ints
  float* bnpar    = statsF + 384;       // 256 floats
  float* attEffs  = statsF + 640;       // 2*320 floats

  // pack all weights into MFMA B-frag order + attEff (idempotent per launch)
  PackArgs pa;
  pa.d[0]  = {w3a,        pw3a0, 64, 128, 8};
  pa.d[1]  = {w3a + 8192, pw3a1, 64, 128, 8};
  pa.d[2]  = {wfa,        pwfa0, 64, 128, 8};
  pa.d[3]  = {wfa + 8192, pwfa1, 64, 128, 8};
  pa.d[4]  = {w3b,        pw3b0, 128, 20, 2};
  pa.d[5]  = {w3b + 2560, pw3b1, 128, 20, 2};
  pa.d[6]  = {wfb,        pwfb0, 128, 20, 2};
  pa.d[7]  = {wfb + 2560, pwfb1, 128, 20, 2};
  pa.d[8]  = {clw1,       pcl1, 128, 128, 8};
  pa.d[9]  = {clw2,       pcl2, 128, 20, 2};
  pa.d[10] = {c1w,        pc1w0, 64, 64, 4};
  pa.d[11] = {c1w + 4096, pc1w1, 64, 64, 4};
  pa.d[12] = {c2w,        pc2w0, 64, 64, 4};
  pa.d[13] = {c2w + 4096, pc2w1, 64, 64, 4};
  k_pack<<<128, 256, 0, stream>>>(pa, fc1w, fc1b, fc2w, fc2b, fc3w, fc3b, attEffs);
  hipMemsetAsync(statsF, 0, 8192, stream);
  hipMemsetAsync(H, 0, (size_t)2 * Cc * NB * 4, stream);      // scanbin self-cleans after
  hipMemsetAsync(counts, 0, (size_t)NV * Cc * 4, stream);     // fill self-cleans after

  for (int s = 0; s < 2; s++) {
    const float* pf_s = pts_feat + (size_t)s * NV * Hh;
    const float* if_s = img_feat + (size_t)s * NIMG * Hh;
    const int*   ci_s = coors_inv + (size_t)s * NPT;
    short* pw1 = s ? pw3a1 : pw3a0;
    short* pw2 = s ? pw3b1 : pw3b0;
    short* pf1 = s ? pwfa1 : pwfa0;
    short* pf2 = s ? pwfb1 : pwfb0;
    short* pc1 = s ? pc1w1 : pc1w0;
    short* pc2 = s ? pc2w1 : pc2w0;
    // bundle A: [scanbin(call1, fuse lovasz of s=0) if s==1] + pred3d MLP + counts/idx
    if (s == 0)
      k_scale_start<false><<<NBLK_MLP + NBLK_CNT, 256, 0, stream>>>(pf_s,
          pw1, b3a, pw2, b3b, pred3d,
          ci_s, labels, counts, p2img, idx, H, HF, 0, lossesC5, gts5);
    else
      k_scale_start<true><<<Cc + NBLK_MLP + NBLK_CNT, 256, 0, stream>>>(pf_s,
          pw1, b3a + 128, pw2, b3b + Cc, pred3d,
          ci_s, labels, counts, p2img, idx, H, HF, 1, lossesC5, gts5);
    // seg_loss(pred3d, vox_lab): voxel-vote fused into fill; CE fused
    k_lov_fill<<<(NV + 255) / 256, 256, 0, stream>>>(pred3d, nullptr, counts, NV, E,
        1.0f / NV, lossAcc, nullptr, nullptr, 0.f);
    k_lov_hist2<<<Cc * NCH, 1024, 0, stream>>>(E, NV, H, HF);
    // bundle B: scanbin(call 2s, pred3d lovasz) + gather/GEMM/att + stats
    k_gatt<<<Cc + NBLK_GA, 256, 0, stream>>>(pf_s, idx, if_s,
        pc1, c1b + s * 64, pc2, c2b + s * 64, attEffs + s * 320,
        y1, y2, attw, partials,
        H, HF, 2 * s, lossesC5, gts5);
    k_colred<<<64, 256, 0, stream>>>(partials, NBLK_GA, red64);
    k_colfinal<<<1, 1024, 0, stream>>>(red64, bn1g + s * 64, bn1b + s * 64,
                                       bn2g + s * 64, bn2b + s * 64, bnpar);
    // fuse -> feats(bf16) + fuse_pred MLP (fused, MFMA)
    k_fusemlp<<<NBLK_GA, 256, 0, stream>>>(y1, y2, attw, bnpar, feats, s * 64,
        pf1, bfa + s * 128, pf2, bfb + s * Cc, fusepred);
    // seg_loss(fuse_pred)*0.5: CE fused + KL fused
    k_lov_fill<<<(NIMG + 255) / 256, 256, 0, stream>>>(fusepred, img_label, nullptr, NIMG, E,
        0.5f / NIMG, lossAcc, pred3d, idx, 0.025f / ((float)NIMG * Cc));
    k_lov_hist2<<<Cc * NCH, 1024, 0, stream>>>(E, NIMG, H, HF);
    // scanbin(call 2s+1) deferred: rides in next bundle (A of s=1, or C)
  }
  // bundle C: scanbin(call3, fuse lovasz of s=1) + final classifier MLP
  k_final_mlp<<<Cc + NBLK_GA, 256, 0, stream>>>(feats,
      pcl1, clb1, pcl2, clb2, fusepred, H, HF, 3, lossesC5, gts5);
  k_lov_fill<<<(NIMG + 255) / 256, 256, 0, stream>>>(fusepred, img_label, nullptr, NIMG, E,
      1.0f / NIMG, lossAcc, nullptr, nullptr, 0.f);
  k_lov_hist2<<<Cc * NCH, 1024, 0, stream>>>(E, NIMG, H, HF);
  k_scanbin5<<<Cc, 256, 0, stream>>>(H, HF, NIMG, 4, lossesC5, gts5);
  k_final<<<1, 1, 0, stream>>>(lossAcc, lossesC5, gts5, (float*)d_out);
}

// Round 3
// 350.416 us; speedup vs baseline: 1.6340x; 1.1304x over previous
//
#include <hip/hip_runtime.h>
#include <stdint.h>

// ---- problem constants (from setup_inputs) ----
static constexpr int NV   = 80000;    // voxels per scale
static constexpr int NPT  = 240000;   // points N
static constexpr int NIMG = 60000;    // B*M image-projected points
static constexpr int Hh   = 64;
static constexpr int Cc   = 20;
static constexpr int NPp  = 120000;   // N per batch
static constexpr int Mm   = 30000;
static constexpr int NB     = 8192;   // error-histogram bins (top-15 float bits)
static constexpr int NCH    = 16;     // chunks per class in hist kernel
static constexpr int NBLK_GA  = (NIMG + 63) / 64;     // 938 gemm_att / mlp blocks
static constexpr int NBLK_MLP = NV / 64;              // 1250 pred3d-mlp blocks
static constexpr int NBLK_CNT = (NPT + 255) / 256;    // 938 counts/idx blocks
static constexpr int NBLK_FILL_NV = (NV + 255) / 256;   // 313
static constexpr int NBLK_FILL_NI = (NIMG + 255) / 256; // 235
static constexpr int NBLK_HIST = Cc * NCH;              // 320
#define BN_EPS 1e-5f

using bf16x8 = __attribute__((ext_vector_type(8))) short;
using f32x4  = __attribute__((ext_vector_type(4))) float;

// ================= small helpers =================
__device__ __forceinline__ float waveReduce(float v) {
  #pragma unroll
  for (int o = 32; o > 0; o >>= 1) v += __shfl_down(v, o);
  return v;
}
__device__ __forceinline__ short f2bf(float f) {   // RNE fp32 -> bf16
  uint32_t u = __float_as_uint(f);
  return (short)((u + 0x7FFFu + ((u >> 16) & 1u)) >> 16);
}
__device__ __forceinline__ float bf2f(uint32_t h) { return __uint_as_float(h << 16); }
__device__ __forceinline__ uint32_t pk2(float a, float b) {
  return ((uint32_t)(uint16_t)f2bf(a)) | ((uint32_t)(uint16_t)f2bf(b) << 16);
}

// ================= weight pre-pack + workspace zero (one dispatch) ========
struct PackDesc { const float* src; short* dst; int K, Nr, nt; };
struct PackArgs { PackDesc d[14]; };

__global__ void __launch_bounds__(256)
k_pack_zero(PackArgs pa,
            const float* __restrict__ fc1w, const float* __restrict__ fc1b,
            const float* __restrict__ fc2w, const float* __restrict__ fc2b,
            const float* __restrict__ fc3w, const float* __restrict__ fc3b,
            float* __restrict__ attEffs,
            uint4* __restrict__ zb, int zq) {
  if (blockIdx.x >= 128) {                      // zero rider: blocks [128,384)
    const uint4 z = make_uint4(0u, 0u, 0u, 0u);
    int i = (blockIdx.x - 128) * 256 + threadIdx.x;
    for (; i < zq; i += 256 * 256) zb[i] = z;
    return;
  }
  const int stride = 128 * 256;
  for (int di = 0; di < 14; di++) {
    const float* src = pa.d[di].src;
    short* dst = pa.d[di].dst;
    int K = pa.d[di].K, Nr = pa.d[di].Nr, ntiles = pa.d[di].nt;
    int total = (K / 32) * ntiles * 512;
    for (int idx = blockIdx.x * blockDim.x + threadIdx.x; idx < total; idx += stride) {
      int j = idx & 7, lane = (idx >> 3) & 63, tile = idx >> 9;
      int nt = tile % ntiles, kt = tile / ntiles;
      int k = kt * 32 + (lane >> 4) * 8 + j;
      int n = nt * 16 + (lane & 15);
      float v = (n < Nr) ? src[(size_t)k * Nr + n] : 0.f;
      dst[idx] = f2bf(v);
    }
  }
  if (blockIdx.x < 2 && threadIdx.x < 64) {
    int s = blockIdx.x, t = threadIdx.x;
    const float* f1w = fc1w + s * 64 * 16; const float* f1b = fc1b + s * 16;
    const float* f2w = fc2w + s * 64 * 16; const float* f2b = fc2b + s * 16;
    const float* f3w = fc3w + s * 64;      const float* f3b = fc3b + s * 2;
    float* aE = attEffs + s * 320;
    float p0 = 0.f, p1 = 0.f, v0 = 0.f, v1 = 0.f;
    #pragma unroll
    for (int j = 0; j < 16; j++) {
      p0 = fmaf(f1w[t * 16 + j], f3w[j * 2], p0);
      p1 = fmaf(f1w[t * 16 + j], f3w[j * 2 + 1], p1);
      v0 = fmaf(f2w[t * 16 + j], f3w[(16 + j) * 2], v0);
      v1 = fmaf(f2w[t * 16 + j], f3w[(16 + j) * 2 + 1], v1);
    }
    aE[t * 2] = p0; aE[t * 2 + 1] = p1;
    aE[128 + t * 2] = v0; aE[128 + t * 2 + 1] = v1;
    if (t == 0) {
      float b0 = f3b[0], b1 = f3b[1];
      for (int j = 0; j < 16; j++) {
        b0 += f1b[j] * f3w[j * 2] + f2b[j] * f3w[(16 + j) * 2];
        b1 += f1b[j] * f3w[j * 2 + 1] + f2b[j] * f3w[(16 + j) * 2 + 1];
      }
      aE[256] = b0; aE[257] = b1;
    }
  }
}

// ====== Lovász scan+bin body (register-resident; NO self-clean) ============
__device__ void scanbin_body(const uint32_t* __restrict__ Hb, const uint32_t* __restrict__ HFb,
                             int n, int call, float* __restrict__ lossesC5,
                             int* __restrict__ gts5, int cls) {
  __shared__ int sWC[4], sWF[4];
  __shared__ float sRedF[4];
  int t = threadIdx.x;
  int lane = t & 63, w = t >> 6;
  const uint32_t* Hc  = Hb  + (size_t)cls * NB;
  const uint32_t* HFc = HFb + (size_t)cls * NB;
  int locC = 0, locF = 0;
  #pragma unroll
  for (int i = 0; i < 8; i++) {
    uint4 cv = *(const uint4*)(Hc  + t * 32 + i * 4);
    uint4 fv = *(const uint4*)(HFc + t * 32 + i * 4);
    locC += (int)(cv.x + cv.y + cv.z + cv.w);
    locF += (int)(fv.x + fv.y + fv.z + fv.w);
  }
  int sc = locC, sf = locF;
  #pragma unroll
  for (int o = 1; o < 64; o <<= 1) {
    int a = __shfl_up(sc, o);
    int b = __shfl_up(sf, o);
    if (lane >= o) { sc += a; sf += b; }
  }
  if (lane == 63) { sWC[w] = sc; sWF[w] = sf; }
  __syncthreads();
  int offC = 0, offF = 0, Ftot = 0;
  #pragma unroll
  for (int ww = 0; ww < 4; ww++) {
    int fc = sWF[ww];
    Ftot += fc;
    if (ww < w) { offC += sWC[ww]; offF += fc; }
  }
  int runC = offC + sc - locC;    // exclusive prefix (ascending bins)
  int runF = offF + sf - locF;
  float gts = (float)Ftot;
  float contrib = 0.f;
  #pragma unroll
  for (int i = 0; i < 8; i++) {
    uint4 cv = *(const uint4*)(Hc  + t * 32 + i * 4);
    uint4 fv = *(const uint4*)(HFc + t * 32 + i * 4);
    uint32_t ca[4] = {cv.x, cv.y, cv.z, cv.w};
    uint32_t fa[4] = {fv.x, fv.y, fv.z, fv.w};
    #pragma unroll
    for (int j = 0; j < 4; j++) {
      int cnt = (int)ca[j], fgc = (int)fa[j];
      runC += cnt; runF += fgc;                          // ascending inclusive
      if (cnt > 0 && Ftot > 0) {
        float r0 = (float)(n - runC);                    // elements with larger err
        float F0 = (float)(Ftot - runF);
        float r1 = r0 + (float)cnt;
        float F1 = F0 + (float)fgc;
        float emean = __uint_as_float((uint32_t)(t * 32 + i * 4 + j) << 17);
        contrib += emean * (r1 / (gts + r1 - F1) - r0 / (gts + r0 - F0));
      }
    }
  }
  contrib = waveReduce(contrib);
  if (lane == 0) sRedF[w] = contrib;
  __syncthreads();
  if (t == 0) {
    lossesC5[call * 32 + cls] = (Ftot > 0) ? (sRedF[0] + sRedF[1] + sRedF[2] + sRedF[3]) : 0.f;
    gts5[call * 32 + cls] = Ftot;
  }
}

// ================= MFMA MLP core: relu(X@W1+b1)@W2+b2 ====================
template<int D>
__device__ __forceinline__ void mfma_mlp_body(const short* sXb, short* sH,
    int r0, int rows,
    const short* __restrict__ pw1, const float* __restrict__ B1,
    const short* __restrict__ pw2, const float* __restrict__ B2,
    float* __restrict__ Out) {
  constexpr int LDB = D + 8;
  constexpr int KT1 = D / 32;
  const int t = threadIdx.x;
  const int lane = t & 63, w = t >> 6;
  const int m = lane & 15, quad = lane >> 4;
  const int rowA = 16 * w + m;
  bf16x8 a1[KT1];
  #pragma unroll
  for (int kt = 0; kt < KT1; kt++)
    a1[kt] = *(const bf16x8*)(sXb + rowA * LDB + kt * 32 + quad * 8);
  const bf16x8* b1 = (const bf16x8*)pw1;
  #pragma unroll
  for (int nt = 0; nt < 8; nt++) {
    f32x4 c = {0.f, 0.f, 0.f, 0.f};
    #pragma unroll
    for (int kt = 0; kt < KT1; kt++)
      c = __builtin_amdgcn_mfma_f32_16x16x32_bf16(a1[kt], b1[(kt * 8 + nt) * 64 + lane], c, 0, 0, 0);
    int col = nt * 16 + m;
    float bc = B1[col];
    #pragma unroll
    for (int reg = 0; reg < 4; reg++)
      sH[(16 * w + quad * 4 + reg) * 136 + col] = f2bf(fmaxf(c[reg] + bc, 0.f));
  }
  __syncthreads();
  bf16x8 a2[4];
  #pragma unroll
  for (int kt = 0; kt < 4; kt++)
    a2[kt] = *(const bf16x8*)(sH + rowA * 136 + kt * 32 + quad * 8);
  const bf16x8* b2 = (const bf16x8*)pw2;
  #pragma unroll
  for (int nt = 0; nt < 2; nt++) {
    f32x4 c = {0.f, 0.f, 0.f, 0.f};
    #pragma unroll
    for (int kt = 0; kt < 4; kt++)
      c = __builtin_amdgcn_mfma_f32_16x16x32_bf16(a2[kt], b2[(kt * 2 + nt) * 64 + lane], c, 0, 0, 0);
    int col = nt * 16 + m;
    if (col < Cc) {
      float bc = B2[col];
      #pragma unroll
      for (int reg = 0; reg < 4; reg++) {
        int gr = r0 + 16 * w + quad * 4 + reg;
        if (gr < rows) Out[(size_t)gr * Cc + col] = c[reg] + bc;
      }
    }
  }
}

// ---- MLP D=64 with f32 staging ----
__device__ void mlp64_body(int bid0, const float* __restrict__ X,
    const short* __restrict__ pw1, const float* __restrict__ B1,
    const short* __restrict__ pw2, const float* __restrict__ B2,
    float* __restrict__ Out, int rows, char* smem) {
  short* sXb = (short*)smem;              // 64*72
  short* sH  = (short*)(smem + 9216);     // 64*136
  int t = threadIdx.x, r0 = bid0 * 64;
  for (int i = t; i < 1024; i += 256) {
    int r = i >> 4, k4 = (i & 15) * 4;
    int gr = r0 + r;
    float4 v = (gr < rows) ? *(const float4*)(X + (size_t)gr * 64 + k4)
                           : make_float4(0.f, 0.f, 0.f, 0.f);
    uint2 p; p.x = pk2(v.x, v.y); p.y = pk2(v.z, v.w);
    *(uint2*)(sXb + r * 72 + k4) = p;
  }
  __syncthreads();
  mfma_mlp_body<64>(sXb, sH, r0, rows, pw1, B1, pw2, B2, Out);
}

// ---- MLP D=128 with bf16 staging ----
__device__ void mlp128_body(int bid0, const uint16_t* __restrict__ Xh,
    const short* __restrict__ pw1, const float* __restrict__ B1,
    const short* __restrict__ pw2, const float* __restrict__ B2,
    float* __restrict__ Out, char* smem) {
  short* sXb = (short*)smem;              // 64*136
  short* sH  = (short*)(smem + 17408);    // 64*136
  int t = threadIdx.x, r0 = bid0 * 64;
  for (int i = t; i < 2048; i += 256) {
    int r = i >> 5, k4 = (i & 31) * 4;
    int gr = r0 + r;
    uint2 p = (gr < NIMG) ? *(const uint2*)(Xh + (size_t)gr * 128 + k4) : make_uint2(0u, 0u);
    *(uint2*)(sXb + r * 136 + k4) = p;
  }
  __syncthreads();
  mfma_mlp_body<128>(sXb, sH, r0, NIMG, pw1, B1, pw2, B2, Out);
}

// ---- counts + gather-idx ----
__device__ void cnt_body(int bid0, const int* __restrict__ ci, const int* __restrict__ labels,
                         int* __restrict__ counts, const int* __restrict__ p2img,
                         int* __restrict__ idx) {
  int i = bid0 * 256 + threadIdx.x;
  if (i < NIMG) {
    int b = (i >= Mm) ? 1 : 0;               // B=2, contiguous batch blocks
    idx[i] = ci[b * NPp + p2img[i]];
  }
  if (i < NPT) atomicAdd(&counts[(size_t)ci[i] * Cc + labels[i]], 1);
}

// ---- BN partials column-reduce (64 blocks) ----
__device__ void colred_body(int bid0, const float* __restrict__ partials,
                            float* __restrict__ red64) {
  int t = threadIdx.x, j = bid0;
  float v = 0.f;
  for (int b = j; b < NBLK_GA; b += 64) v += partials[(size_t)b * 256 + t];
  red64[j * 256 + t] = v;
}

// ---- Lovász fill body (CE + optional KL + optional voxel-vote) ----
__device__ void fill_body(int bid0, const float* __restrict__ logits,
                          const int* __restrict__ lab, const int* __restrict__ vcnt,
                          int n, uint16_t* __restrict__ E,
                          float ceScale, float* __restrict__ lossAcc,
                          const float* __restrict__ pred3d, const int* __restrict__ idxg,
                          float klScale) {
  int i = bid0 * 256 + threadIdx.x;
  float total = 0.f;
  if (i < n) {
    int lb;
    if (vcnt) {
      const int* crow = vcnt + (size_t)i * Cc;
      int best = crow[0], arg = 0;
      #pragma unroll
      for (int k = 1; k < Cc; k++) {
        int ck = crow[k];
        if (ck > best) { best = ck; arg = k; }   // first-max
      }
      lb = arg;
    } else {
      lb = lab[i];
    }
    const float* l = logits + (size_t)i * Cc;
    float m = l[0];
    #pragma unroll
    for (int c = 1; c < Cc; c++) m = fmaxf(m, l[c]);
    float ex[Cc]; float se = 0.f;
    #pragma unroll
    for (int c = 0; c < Cc; c++) { ex[c] = expf(l[c] - m); se += ex[c]; }
    float inv = 1.f / se;
    float lse = logf(se);
    total = -(l[lb] - m - lse) * ceScale;
    #pragma unroll
    for (int c = 0; c < Cc; c++) {
      float prob = ex[c] * inv;
      int fg = (c == lb) ? 1 : 0;
      float err = fg ? (1.f - prob) : prob;
      err = fmaxf(err, 0.f);
      uint32_t key = __float_as_uint(err) >> 17;     // < 8192
      E[(size_t)c * n + i] = (uint16_t)((key << 1) | (uint32_t)fg);
    }
    if (pred3d) {
      const float* q = pred3d + (size_t)idxg[i] * Cc;
      float mq = q[0];
      #pragma unroll
      for (int c = 1; c < Cc; c++) mq = fmaxf(mq, q[c]);
      float sq = 0.f;
      #pragma unroll
      for (int c = 0; c < Cc; c++) sq += expf(q[c] - mq);
      float lsq = logf(sq);
      float kl = 0.f;
      #pragma unroll
      for (int c = 0; c < Cc; c++) {
        float lf = l[c] - m - lse;
        float pf = ex[c] * inv;
        float lq = q[c] - mq - lsq;
        kl += pf * (lf - lq);
      }
      total += kl * klScale;
    }
  }
  total = waveReduce(total);
  __shared__ float sh[4];
  int lane = threadIdx.x & 63, w = threadIdx.x >> 6;
  if (lane == 0) sh[w] = total;
  __syncthreads();
  if (threadIdx.x == 0) atomicAdd(lossAcc, sh[0] + sh[1] + sh[2] + sh[3]);
}

// ---- LDS-privatized histogram body (256 threads) ----
__device__ void hist_body(int bid0, const uint16_t* __restrict__ E, int n,
                          uint32_t* __restrict__ H, uint32_t* __restrict__ HF, char* smem) {
  uint32_t* lcf = (uint32_t*)smem;                 // 8192 u32 = 32 KB
  int t = threadIdx.x;
  int cls = bid0 / NCH, ch = bid0 - cls * NCH;
  int CHsz = (n + NCH - 1) / NCH;
  int i0 = ch * CHsz;
  int i1 = min(n, i0 + CHsz);
  for (int b = t; b < NB; b += 256) lcf[b] = 0u;
  __syncthreads();
  const uint16_t* Ec = E + (size_t)cls * n;
  for (int i = i0 + t; i < i1; i += 256) {
    uint32_t p = Ec[i];
    atomicAdd(&lcf[p >> 1], 0x10000u | (p & 1u));    // count hi16, fg lo16
  }
  __syncthreads();
  uint32_t* Hc  = H  + (size_t)cls * NB;
  uint32_t* HFc = HF + (size_t)cls * NB;
  for (int b = t; b < NB; b += 256) {
    uint32_t v = lcf[b];
    if (v) {
      atomicAdd(&Hc[b], v >> 16);
      uint32_t f = v & 0xFFFFu;
      if (f) atomicAdd(&HFc[b], f);
    }
  }
}

// ---- gather + dual 64x64 GEMM + att + per-block BN partials ----
__device__ void gatt_body(int bid0, const float* __restrict__ pts, const int* __restrict__ idx,
                          const float* __restrict__ img,
                          const short* __restrict__ pc1, const float* __restrict__ c1b,
                          const short* __restrict__ pc2, const float* __restrict__ c2b,
                          const float* __restrict__ attEff,
                          uint16_t* __restrict__ y1, uint16_t* __restrict__ y2,
                          float* __restrict__ attw, float* __restrict__ partials,
                          char* smem) {
  short* sP = (short*)smem;                         // 64*72
  short* sV = (short*)(smem + 9216);                // 64*72
  float* sAtt  = (float*)(smem + 18432);            // 64*8
  float* sStat = (float*)(smem + 20480);            // 1024
  int t = threadIdx.x;
  int r0 = bid0 * 64;
  for (int i = t; i < 1024; i += 256) {
    int r = i >> 4, q = i & 15;
    int gr = r0 + r;
    float4 vp = make_float4(0.f, 0.f, 0.f, 0.f), vv = vp;
    if (gr < NIMG) {
      vp = *(const float4*)(pts + (size_t)idx[gr] * 64 + q * 4);
      vv = *(const float4*)(img + (size_t)gr * 64 + q * 4);
    }
    uint2 pp, qv;
    pp.x = pk2(vp.x, vp.y); pp.y = pk2(vp.z, vp.w);
    qv.x = pk2(vv.x, vv.y); qv.y = pk2(vv.z, vv.w);
    *(uint2*)(sP + r * 72 + q * 4) = pp;
    *(uint2*)(sV + r * 72 + q * 4) = qv;
  }
  __syncthreads();
  {
    int r = t & 63, qq = t >> 6;
    const float* aP = attEff;
    const float* aV = attEff + 128;
    float l0 = 0.f, l1 = 0.f;
    for (int k = qq * 16; k < qq * 16 + 16; k += 4) {
      uint2 up = *(const uint2*)(sP + r * 72 + k);
      uint2 uv = *(const uint2*)(sV + r * 72 + k);
      float p0 = bf2f(up.x & 0xffff), p1 = bf2f(up.x >> 16);
      float p2 = bf2f(up.y & 0xffff), p3 = bf2f(up.y >> 16);
      float v0 = bf2f(uv.x & 0xffff), v1 = bf2f(uv.x >> 16);
      float v2 = bf2f(uv.y & 0xffff), v3 = bf2f(uv.y >> 16);
      float4 wa = *(const float4*)(aP + 2 * k);
      float4 wb = *(const float4*)(aP + 2 * k + 4);
      l0 += p0 * wa.x + p1 * wa.z + p2 * wb.x + p3 * wb.z;
      l1 += p0 * wa.y + p1 * wa.w + p2 * wb.y + p3 * wb.w;
      float4 ua = *(const float4*)(aV + 2 * k);
      float4 ub = *(const float4*)(aV + 2 * k + 4);
      l0 += v0 * ua.x + v1 * ua.z + v2 * ub.x + v3 * ub.z;
      l1 += v0 * ua.y + v1 * ua.w + v2 * ub.y + v3 * ub.w;
    }
    sAtt[r * 8 + qq * 2] = l0;
    sAtt[r * 8 + qq * 2 + 1] = l1;
  }
  const int lane = t & 63, w = t >> 6;
  const int m = lane & 15, quad = lane >> 4;
  const int rowA = 16 * w + m;
  bf16x8 ap[2], av[2];
  #pragma unroll
  for (int kt = 0; kt < 2; kt++) {
    ap[kt] = *(const bf16x8*)(sP + rowA * 72 + kt * 32 + quad * 8);
    av[kt] = *(const bf16x8*)(sV + rowA * 72 + kt * 32 + quad * 8);
  }
  const bf16x8* b1 = (const bf16x8*)pc1;
  const bf16x8* b2 = (const bf16x8*)pc2;
  #pragma unroll
  for (int nt = 0; nt < 4; nt++) {
    int col = nt * 16 + m;
    f32x4 c1 = {0.f, 0.f, 0.f, 0.f}, c2 = {0.f, 0.f, 0.f, 0.f};
    #pragma unroll
    for (int kt = 0; kt < 2; kt++) {
      c1 = __builtin_amdgcn_mfma_f32_16x16x32_bf16(ap[kt], b1[(kt * 4 + nt) * 64 + lane], c1, 0, 0, 0);
      c2 = __builtin_amdgcn_mfma_f32_16x16x32_bf16(av[kt], b2[(kt * 4 + nt) * 64 + lane], c2, 0, 0, 0);
    }
    float bb1 = c1b[col], bb2 = c2b[col];
    float s1 = 0.f, q1 = 0.f, s2 = 0.f, q2 = 0.f;
    #pragma unroll
    for (int reg = 0; reg < 4; reg++) {
      int gr = r0 + 16 * w + quad * 4 + reg;
      if (gr < NIMG) {
        float v1 = c1[reg] + bb1, v2 = c2[reg] + bb2;
        y1[(size_t)gr * 64 + col] = (uint16_t)f2bf(v1);
        y2[(size_t)gr * 64 + col] = (uint16_t)f2bf(v2);
        s1 += v1; q1 = fmaf(v1, v1, q1);
        s2 += v2; q2 = fmaf(v2, v2, q2);
      }
    }
    s1 += __shfl_down(s1, 32); s1 += __shfl_down(s1, 16);
    q1 += __shfl_down(q1, 32); q1 += __shfl_down(q1, 16);
    s2 += __shfl_down(s2, 32); s2 += __shfl_down(s2, 16);
    q2 += __shfl_down(q2, 32); q2 += __shfl_down(q2, 16);
    if (lane < 16) {
      float* base = sStat + (w * 4 + nt) * 64 + lane;
      base[0]  = s1;
      base[16] = q1;
      base[32] = s2;
      base[48] = q2;
    }
  }
  __syncthreads();
  {
    int kind = t >> 6, col = t & 63;
    int nt = col >> 4, mm = col & 15;
    float v = 0.f;
    #pragma unroll
    for (int ww = 0; ww < 4; ww++)
      v += sStat[(ww * 4 + nt) * 64 + kind * 16 + mm];
    partials[(size_t)bid0 * 256 + kind * 64 + col] = v;
  }
  if (t < 64) {
    int gr = r0 + t;
    if (gr < NIMG) {
      float l0 = attEff[256] + sAtt[t * 8] + sAtt[t * 8 + 2] + sAtt[t * 8 + 4] + sAtt[t * 8 + 6];
      float l1 = attEff[257] + sAtt[t * 8 + 1] + sAtt[t * 8 + 3] + sAtt[t * 8 + 5] + sAtt[t * 8 + 7];
      attw[gr * 2]     = 1.f / (1.f + expf(-l0));
      attw[gr * 2 + 1] = 1.f / (1.f + expf(-l1));
    }
  }
}

// ---- fuse (BN from red64, inline) -> feats + fuse-MLP ----
__device__ void fusemlp_body(int bid0,
    const uint16_t* __restrict__ y1, const uint16_t* __restrict__ y2,
    const float* __restrict__ attw, const float* __restrict__ red64,
    const float* __restrict__ g1, const float* __restrict__ be1,
    const float* __restrict__ g2, const float* __restrict__ be2,
    uint16_t* __restrict__ feats, int s64,
    const short* __restrict__ pw1, const float* __restrict__ B1,
    const short* __restrict__ pw2, const float* __restrict__ B2,
    float* __restrict__ Out, char* smem) {
  short* sXb = (short*)smem;                    // 64*72
  short* sH  = (short*)(smem + 9216);           // 64*136
  float* sBn = (float*)(smem + 9216 + 17408);   // 256 floats
  int t = threadIdx.x, r0 = bid0 * 64;
  // inline BN finalize: reduce red64 (64 x 256, L2-hot) then compute scale/shift
  float acc = 0.f;
  #pragma unroll 8
  for (int b = 0; b < 64; b++) acc += red64[b * 256 + t];
  float* sSum = (float*)sH;                     // scratch (sH unused until MLP1 out)
  sSum[t] = acc;
  __syncthreads();
  if (t < 64) {
    float nn = (float)NIMG;
    float mu1 = sSum[t] / nn;
    float var1 = sSum[64 + t] / nn - mu1 * mu1;
    float a1 = g1[t] / sqrtf(var1 + BN_EPS);
    sBn[t] = a1; sBn[64 + t] = be1[t] - mu1 * a1;
    float mu2 = sSum[128 + t] / nn;
    float var2 = sSum[192 + t] / nn - mu2 * mu2;
    float a2 = g2[t] / sqrtf(var2 + BN_EPS);
    sBn[128 + t] = a2; sBn[192 + t] = be2[t] - mu2 * a2;
  }
  __syncthreads();
  for (int i = t; i < 1024; i += 256) {
    int r = i >> 4, q = i & 15;
    int gr = r0 + r;
    uint2 zp = make_uint2(0u, 0u);
    if (gr < NIMG) {
      float4 a1 = *(const float4*)(sBn + q * 4);
      float4 c1 = *(const float4*)(sBn + 64 + q * 4);
      float4 a2 = *(const float4*)(sBn + 128 + q * 4);
      float4 c2 = *(const float4*)(sBn + 192 + q * 4);
      uint2 u1 = *(const uint2*)(y1 + (size_t)gr * 64 + q * 4);
      uint2 u2 = *(const uint2*)(y2 + (size_t)gr * 64 + q * 4);
      float w0 = attw[gr * 2], w1 = attw[gr * 2 + 1];
      float zx = fmaxf(fmaf(bf2f(u1.x & 0xffff), a1.x, c1.x), 0.f) * w0
               + fmaxf(fmaf(bf2f(u2.x & 0xffff), a2.x, c2.x), 0.f) * w1;
      float zy = fmaxf(fmaf(bf2f(u1.x >> 16),   a1.y, c1.y), 0.f) * w0
               + fmaxf(fmaf(bf2f(u2.x >> 16),   a2.y, c2.y), 0.f) * w1;
      float zz = fmaxf(fmaf(bf2f(u1.y & 0xffff), a1.z, c1.z), 0.f) * w0
               + fmaxf(fmaf(bf2f(u2.y & 0xffff), a2.z, c2.z), 0.f) * w1;
      float zw = fmaxf(fmaf(bf2f(u1.y >> 16),   a1.w, c1.w), 0.f) * w0
               + fmaxf(fmaf(bf2f(u2.y >> 16),   a2.w, c2.w), 0.f) * w1;
      zp.x = pk2(zx, zy); zp.y = pk2(zz, zw);
      *(uint2*)(feats + (size_t)gr * 128 + s64 + q * 4) = zp;
    }
    *(uint2*)(sXb + r * 72 + q * 4) = zp;
  }
  __syncthreads();
  mfma_mlp_body<64>(sXb, sH, r0, NIMG, pw1, B1, pw2, B2, Out);
}

// ===================== wrapper kernels (block-range bundles) ===============
// D2: both scales' pred3d MLP + counts/idx
__global__ void __launch_bounds__(256)
k_start2(const float* __restrict__ X0, const float* __restrict__ X1,
         const short* pw1_0, const float* B1_0, const short* pw2_0, const float* B2_0, float* out0,
         const short* pw1_1, const float* B1_1, const short* pw2_1, const float* B2_1, float* out1,
         const int* __restrict__ ci0, const int* __restrict__ ci1,
         const int* __restrict__ labels, const int* __restrict__ p2img,
         int* __restrict__ counts0, int* __restrict__ counts1,
         int* __restrict__ idx0, int* __restrict__ idx1) {
  __shared__ char smem[26624];
  int bid = blockIdx.x;
  if (bid < NBLK_MLP) { mlp64_body(bid, X0, pw1_0, B1_0, pw2_0, B2_0, out0, NV, smem); return; }
  bid -= NBLK_MLP;
  if (bid < NBLK_MLP) { mlp64_body(bid, X1, pw1_1, B1_1, pw2_1, B2_1, out1, NV, smem); return; }
  bid -= NBLK_MLP;
  if (bid < NBLK_CNT) { cnt_body(bid, ci0, labels, counts0, p2img, idx0); return; }
  cnt_body(bid - NBLK_CNT, ci1, labels, counts1, p2img, idx1);
}

// D3: both NV lovász fills (voxel-vote inline)
__global__ void __launch_bounds__(256)
k_fill2(const float* __restrict__ l0, const int* __restrict__ vc0, uint16_t* __restrict__ E0,
        const float* __restrict__ l1, const int* __restrict__ vc1, uint16_t* __restrict__ E1,
        float ce, float* __restrict__ lossAcc) {
  if (blockIdx.x < NBLK_FILL_NV)
    fill_body(blockIdx.x, l0, nullptr, vc0, NV, E0, ce, lossAcc, nullptr, nullptr, 0.f);
  else
    fill_body(blockIdx.x - NBLK_FILL_NV, l1, nullptr, vc1, NV, E1, ce, lossAcc, nullptr, nullptr, 0.f);
}

// D4: both NV histograms
__global__ void __launch_bounds__(256)
k_hist2x(const uint16_t* __restrict__ E0, uint32_t* H0, uint32_t* HF0,
         const uint16_t* __restrict__ E1, uint32_t* H1, uint32_t* HF1, int n) {
  __shared__ char smem[32768];
  if (blockIdx.x < NBLK_HIST) hist_body(blockIdx.x, E0, n, H0, HF0, smem);
  else hist_body(blockIdx.x - NBLK_HIST, E1, n, H1, HF1, smem);
}

// D5/D6: gatt + optional 2 scans + optional colred rider
__global__ void __launch_bounds__(256)
k_gattx(const float* __restrict__ pts, const int* __restrict__ idx, const float* __restrict__ img,
        const short* pc1, const float* c1b, const short* pc2, const float* c2b,
        const float* attEff, uint16_t* y1, uint16_t* y2, float* attw, float* partials,
        const uint32_t* Ha, const uint32_t* HFa, int na, int calla,
        const uint32_t* Hb, const uint32_t* HFb, int nb, int callb,
        int nscan,
        const float* crPart, float* crRed,
        float* lossesC5, int* gts5) {
  __shared__ char smem[24576];
  int bid = blockIdx.x;
  if (bid < nscan * Cc) {
    if (bid < Cc) scanbin_body(Ha, HFa, na, calla, lossesC5, gts5, bid);
    else scanbin_body(Hb, HFb, nb, callb, lossesC5, gts5, bid - Cc);
    return;
  }
  bid -= nscan * Cc;
  if (crPart) {
    if (bid < 64) { colred_body(bid, crPart, crRed); return; }
    bid -= 64;
  }
  gatt_body(bid, pts, idx, img, pc1, c1b, pc2, c2b, attEff, y1, y2, attw, partials, smem);
}

// D7/D8: fusemlp + colred rider OR fill rider
__global__ void __launch_bounds__(256)
k_fusex(const uint16_t* y1, const uint16_t* y2, const float* attw, const float* red64,
        const float* g1, const float* be1, const float* g2, const float* be2,
        uint16_t* feats, int s64,
        const short* pw1, const float* B1, const short* pw2, const float* B2, float* Out,
        const float* crPart, float* crRed,
        const float* fl_logits, const int* fl_lab, uint16_t* fl_E, float fl_ce,
        const float* fl_pred, const int* fl_idx, float fl_kl, float* lossAcc) {
  __shared__ char smem[27648];
  int bid = blockIdx.x;
  if (bid < NBLK_GA) {
    fusemlp_body(bid, y1, y2, attw, red64, g1, be1, g2, be2, feats, s64,
                 pw1, B1, pw2, B2, Out, smem);
    return;
  }
  bid -= NBLK_GA;
  if (crPart) { colred_body(bid, crPart, crRed); return; }
  fill_body(bid, fl_logits, fl_lab, nullptr, NIMG, fl_E, fl_ce, lossAcc, fl_pred, fl_idx, fl_kl);
}

// D9: fill(call3) + hist(call1)
__global__ void __launch_bounds__(256)
k_fill_hist(const float* __restrict__ l, const int* __restrict__ lab, uint16_t* Ew, float ce,
            const float* __restrict__ pred, const int* __restrict__ idxg, float kl,
            float* lossAcc,
            const uint16_t* __restrict__ Er, int nh, uint32_t* H, uint32_t* HF) {
  __shared__ char smem[32768];
  if (blockIdx.x < NBLK_FILL_NI)
    fill_body(blockIdx.x, l, lab, nullptr, NIMG, Ew, ce, lossAcc, pred, idxg, kl);
  else
    hist_body(blockIdx.x - NBLK_FILL_NI, Er, nh, H, HF, smem);
}

// D10: final classifier MLP + hist(call3) + scan(call1)
__global__ void __launch_bounds__(256)
k_finx(const uint16_t* __restrict__ Xh,
       const short* pw1, const float* B1, const short* pw2, const float* B2, float* Out,
       const uint16_t* __restrict__ Er, int nh, uint32_t* Hr, uint32_t* HFr,
       const uint32_t* Hs, const uint32_t* HFs, int ns, int calls,
       float* lossesC5, int* gts5) {
  __shared__ char smem[34816];
  int bid = blockIdx.x;
  if (bid < NBLK_GA) { mlp128_body(bid, Xh, pw1, B1, pw2, B2, Out, smem); return; }
  bid -= NBLK_GA;
  if (bid < NBLK_HIST) { hist_body(bid, Er, nh, Hr, HFr, smem); return; }
  scanbin_body(Hs, HFs, ns, calls, lossesC5, gts5, bid - NBLK_HIST);
}

// D11: fill(call4) + scan(call3)
__global__ void __launch_bounds__(256)
k_fill_scan(const float* __restrict__ l, const int* __restrict__ lab, uint16_t* Ew, float ce,
            float* lossAcc,
            const uint32_t* Hs, const uint32_t* HFs, int ns, int calls,
            float* lossesC5, int* gts5) {
  if (blockIdx.x < NBLK_FILL_NI)
    fill_body(blockIdx.x, l, lab, nullptr, NIMG, Ew, ce, lossAcc, nullptr, nullptr, 0.f);
  else
    scanbin_body(Hs, HFs, ns, calls, lossesC5, gts5, blockIdx.x - NBLK_FILL_NI);
}

// D12: hist(call4)
__global__ void __launch_bounds__(256)
k_hist1(const uint16_t* __restrict__ E, int n, uint32_t* H, uint32_t* HF) {
  __shared__ char smem[32768];
  hist_body(blockIdx.x, E, n, H, HF, smem);
}

// D13: scan(call4)
__global__ void __launch_bounds__(256)
k_scanbin5(const uint32_t* Hb, const uint32_t* HFb, int n, int call,
           float* lossesC5, int* gts5) {
  scanbin_body(Hb, HFb, n, call, lossesC5, gts5, blockIdx.x);
}

// D14: fold 5 lovász combines + output
__global__ void k_final(const float* __restrict__ lossAcc,
                        const float* __restrict__ lossesC5, const int* __restrict__ gts5,
                        float* __restrict__ out) {
  const float coefs[5] = {1.0f, 0.5f, 1.0f, 0.5f, 1.0f};
  float loss = lossAcc[0];
  for (int call = 0; call < 5; call++) {
    float s = 0.f; int np = 0;
    for (int c = 0; c < Cc; c++)
      if (gts5[call * 32 + c] > 0) { s += lossesC5[call * 32 + c]; np++; }
    loss += coefs[call] * s / (float)(np > 0 ? np : 1);
  }
  out[0] = loss;
}

// ================= host-side driver =================
extern "C" void kernel_launch(void* const* d_in, const int* in_sizes, int n_in,
                              void* d_out, int out_size, void* d_ws, size_t ws_size,
                              hipStream_t stream) {
  const float* img_feat = (const float*)d_in[0];
  const float* pts_feat = (const float*)d_in[1];
  const int* coors_inv  = (const int*)d_in[2];
  const int* labels     = (const int*)d_in[3];
  const int* img_label  = (const int*)d_in[4];
  const int* p2img      = (const int*)d_in[5];
  const float* w3a = (const float*)d_in[6];
  const float* b3a = (const float*)d_in[7];
  const float* w3b = (const float*)d_in[8];
  const float* b3b = (const float*)d_in[9];
  const float* wfa = (const float*)d_in[10];
  const float* bfa = (const float*)d_in[11];
  const float* wfb = (const float*)d_in[12];
  const float* bfb = (const float*)d_in[13];
  const float* fc1w = (const float*)d_in[14];
  const float* fc1b = (const float*)d_in[15];
  const float* fc2w = (const float*)d_in[16];
  const float* fc2b = (const float*)d_in[17];
  const float* fc3w = (const float*)d_in[18];
  const float* fc3b = (const float*)d_in[19];
  const float* c1w  = (const float*)d_in[20];
  const float* c1b  = (const float*)d_in[21];
  const float* bn1g = (const float*)d_in[22];
  const float* bn1b = (const float*)d_in[23];
  const float* c2w  = (const float*)d_in[24];
  const float* c2b  = (const float*)d_in[25];
  const float* bn2g = (const float*)d_in[26];
  const float* bn2b = (const float*)d_in[27];
  const float* clw1 = (const float*)d_in[28];
  const float* clb1 = (const float*)d_in[29];
  const float* clw2 = (const float*)d_in[30];
  const float* clb2 = (const float*)d_in[31];
  (void)in_sizes; (void)n_in; (void)out_size; (void)ws_size;

  // ---- workspace layout ----
  char* ws = (char*)d_ws;
  size_t off = 0;
  auto alloc = [&](size_t bytes) { void* p = ws + off; off += (bytes + 255) & ~(size_t)255; return p; };
  uint16_t* feats = (uint16_t*)alloc((size_t)NIMG * 128 * 2);
  float* pred3d0 = (float*)alloc((size_t)NV * Cc * 4);
  float* pred3d1 = (float*)alloc((size_t)NV * Cc * 4);
  int* idx0 = (int*)alloc((size_t)NIMG * 4);
  int* idx1 = (int*)alloc((size_t)NIMG * 4);
  uint16_t* y1a = (uint16_t*)alloc((size_t)NIMG * Hh * 2);
  uint16_t* y2a = (uint16_t*)alloc((size_t)NIMG * Hh * 2);
  uint16_t* y1b = (uint16_t*)alloc((size_t)NIMG * Hh * 2);
  uint16_t* y2b = (uint16_t*)alloc((size_t)NIMG * Hh * 2);
  uint16_t* E0 = (uint16_t*)alloc((size_t)Cc * NV * 2);
  uint16_t* E1 = (uint16_t*)alloc((size_t)Cc * NV * 2);
  float* partials0 = (float*)alloc((size_t)NBLK_GA * 256 * 4);
  float* partials1 = (float*)alloc((size_t)NBLK_GA * 256 * 4);
  float* red64_0 = (float*)alloc(64 * 256 * 4);
  float* red64_1 = (float*)alloc(64 * 256 * 4);
  float* attw0 = (float*)alloc((size_t)NIMG * 2 * 4);
  float* attw1 = (float*)alloc((size_t)NIMG * 2 * 4);
  float* fusepred0 = (float*)alloc((size_t)NIMG * Cc * 4);   // also reused as final logits
  float* fusepred1 = (float*)alloc((size_t)NIMG * Cc * 4);
  short* pwAll = (short*)alloc(86016 * 2);
  short* pw3a0 = pwAll,          * pw3a1 = pwAll + 8192;
  short* pwfa0 = pwAll + 16384,  * pwfa1 = pwAll + 24576;
  short* pw3b0 = pwAll + 32768,  * pw3b1 = pwAll + 36864;
  short* pwfb0 = pwAll + 40960,  * pwfb1 = pwAll + 45056;
  short* pcl1  = pwAll + 49152;
  short* pcl2  = pwAll + 65536;
  short* pc1w0 = pwAll + 69632,  * pc1w1 = pwAll + 73728;
  short* pc2w0 = pwAll + 77824,  * pc2w1 = pwAll + 81920;
  float* attEffs = (float*)alloc(2 * 320 * 4);
  // ---- contiguous zero region: stats + 5x(H,HF) + counts0/1 ----
  size_t zsize = 1024 + (size_t)5 * 2 * Cc * NB * 4 + (size_t)2 * NV * Cc * 4;
  char* zbase = (char*)alloc(zsize);
  float* lossAcc  = (float*)zbase;                 // [0]
  float* lossesC5 = (float*)zbase + 32;            // 5*32
  int*   gts5     = (int*)((float*)zbase + 192);   // 5*32 ints
  uint32_t* Hbase = (uint32_t*)(zbase + 1024);
  auto Hc  = [&](int call) { return Hbase + (size_t)call * 2 * Cc * NB; };
  auto HFc = [&](int call) { return Hbase + (size_t)call * 2 * Cc * NB + (size_t)Cc * NB; };
  int* counts0 = (int*)(zbase + 1024 + (size_t)5 * 2 * Cc * NB * 4);
  int* counts1 = counts0 + (size_t)NV * Cc;
  int zq = (int)(zsize / 16);

  const float kl = 0.025f / ((float)NIMG * Cc);
  const float* pf0 = pts_feat;
  const float* pf1 = pts_feat + (size_t)NV * Hh;
  const float* if0 = img_feat;
  const float* if1 = img_feat + (size_t)NIMG * Hh;
  const int* ci0 = coors_inv;
  const int* ci1 = coors_inv + NPT;

  // D1: pack weights + zero workspace region
  PackArgs pa;
  pa.d[0]  = {w3a,        pw3a0, 64, 128, 8};
  pa.d[1]  = {w3a + 8192, pw3a1, 64, 128, 8};
  pa.d[2]  = {wfa,        pwfa0, 64, 128, 8};
  pa.d[3]  = {wfa + 8192, pwfa1, 64, 128, 8};
  pa.d[4]  = {w3b,        pw3b0, 128, 20, 2};
  pa.d[5]  = {w3b + 2560, pw3b1, 128, 20, 2};
  pa.d[6]  = {wfb,        pwfb0, 128, 20, 2};
  pa.d[7]  = {wfb + 2560, pwfb1, 128, 20, 2};
  pa.d[8]  = {clw1,       pcl1, 128, 128, 8};
  pa.d[9]  = {clw2,       pcl2, 128, 20, 2};
  pa.d[10] = {c1w,        pc1w0, 64, 64, 4};
  pa.d[11] = {c1w + 4096, pc1w1, 64, 64, 4};
  pa.d[12] = {c2w,        pc2w0, 64, 64, 4};
  pa.d[13] = {c2w + 4096, pc2w1, 64, 64, 4};
  k_pack_zero<<<128 + 256, 256, 0, stream>>>(pa, fc1w, fc1b, fc2w, fc2b, fc3w, fc3b,
                                             attEffs, (uint4*)zbase, zq);

  // D2: both scales pred3d MLP + counts/idx
  k_start2<<<2 * NBLK_MLP + 2 * NBLK_CNT, 256, 0, stream>>>(
      pf0, pf1,
      pw3a0, b3a, pw3b0, b3b, pred3d0,
      pw3a1, b3a + 128, pw3b1, b3b + Cc, pred3d1,
      ci0, ci1, labels, p2img, counts0, counts1, idx0, idx1);

  // D3: both NV fills (vote inline)
  k_fill2<<<2 * NBLK_FILL_NV, 256, 0, stream>>>(pred3d0, counts0, E0,
                                                pred3d1, counts1, E1,
                                                1.0f / NV, lossAcc);

  // D4: both NV histograms (call0 -> H0, call2 -> H2)
  k_hist2x<<<2 * NBLK_HIST, 256, 0, stream>>>(E0, Hc(0), HFc(0), E1, Hc(2), HFc(2), NV);

  // D5: gatt(s0) + scan(call0) + scan(call2)
  k_gattx<<<2 * Cc + NBLK_GA, 256, 0, stream>>>(
      pf0, idx0, if0, pc1w0, c1b, pc2w0, c2b, attEffs,
      y1a, y2a, attw0, partials0,
      Hc(0), HFc(0), NV, 0, Hc(2), HFc(2), NV, 2, 2,
      nullptr, nullptr, lossesC5, gts5);

  // D6: gatt(s1) + colred(s0)
  k_gattx<<<64 + NBLK_GA, 256, 0, stream>>>(
      pf1, idx1, if1, pc1w1, c1b + 64, pc2w1, c2b + 64, attEffs + 320,
      y1b, y2b, attw1, partials1,
      nullptr, nullptr, 0, 0, nullptr, nullptr, 0, 0, 0,
      partials0, red64_0, lossesC5, gts5);

  // D7: fusemlp(s0, BN inline) + colred(s1)
  k_fusex<<<NBLK_GA + 64, 256, 0, stream>>>(
      y1a, y2a, attw0, red64_0, bn1g, bn1b, bn2g, bn2b, feats, 0,
      pwfa0, bfa, pwfb0, bfb, fusepred0,
      partials1, red64_1,
      nullptr, nullptr, nullptr, 0.f, nullptr, nullptr, 0.f, lossAcc);

  // D8: fusemlp(s1) + fill(call1: fuse loss s0, CE+KL)
  k_fusex<<<NBLK_GA + NBLK_FILL_NI, 256, 0, stream>>>(
      y1b, y2b, attw1, red64_1, bn1g + 64, bn1b + 64, bn2g + 64, bn2b + 64, feats, 64,
      pwfa1, bfa + 128, pwfb1, bfb + Cc, fusepred1,
      nullptr, nullptr,
      fusepred0, img_label, E0, 0.5f / NIMG, pred3d0, idx0, kl, lossAcc);

  // D9: fill(call3: fuse loss s1) + hist(call1)
  k_fill_hist<<<NBLK_FILL_NI + NBLK_HIST, 256, 0, stream>>>(
      fusepred1, img_label, E1, 0.5f / NIMG, pred3d1, idx1, kl, lossAcc,
      E0, NIMG, Hc(1), HFc(1));

  // D10: final classifier MLP + hist(call3) + scan(call1)
  k_finx<<<NBLK_GA + NBLK_HIST + Cc, 256, 0, stream>>>(
      feats, pcl1, clb1, pcl2, clb2, fusepred0,
      E1, NIMG, Hc(3), HFc(3),
      Hc(1), HFc(1), NIMG, 1, lossesC5, gts5);

  // D11: fill(call4: final loss) + scan(call3)
  k_fill_scan<<<NBLK_FILL_NI + Cc, 256, 0, stream>>>(
      fusepred0, img_label, E0, 1.0f / NIMG, lossAcc,
      Hc(3), HFc(3), NIMG, 3, lossesC5, gts5);

  // D12: hist(call4)
  k_hist1<<<NBLK_HIST, 256, 0, stream>>>(E0, NIMG, Hc(4), HFc(4));

  // D13: scan(call4)
  k_scanbin5<<<Cc, 256, 0, stream>>>(Hc(4), HFc(4), NIMG, 4, lossesC5, gts5);

  // D14: fold + output
  k_final<<<1, 1, 0, stream>>>(lossAcc, lossesC5, gts5, (float*)d_out);
}

// Round 4
// 347.069 us; speedup vs baseline: 1.6498x; 1.0096x over previous
//
#include <hip/hip_runtime.h>
#include <stdint.h>

// ---- problem constants (from setup_inputs) ----
static constexpr int NV   = 80000;    // voxels per scale
static constexpr int NPT  = 240000;   // points N
static constexpr int NIMG = 60000;    // B*M image-projected points
static constexpr int Hh   = 64;
static constexpr int Cc   = 20;
static constexpr int NPp  = 120000;   // N per batch
static constexpr int Mm   = 30000;
static constexpr int NB     = 8192;   // error-histogram bins (top-15 float bits)
static constexpr int NCH    = 16;     // chunks per class in hist kernel
static constexpr int NBLK_GA  = (NIMG + 63) / 64;     // 938
static constexpr int NBLK_MLP = NV / 64;              // 1250
static constexpr int NBLK_CNT = (NPT + 255) / 256;    // 938
static constexpr int NBLK_FILL_NV = (NV + 255) / 256;   // 313
static constexpr int NBLK_FILL_NI = (NIMG + 255) / 256; // 235
static constexpr int NBLK_HIST = Cc * NCH;              // 320
static constexpr int NBLK_IDX  = (NIMG + 255) / 256;    // 235
#define BN_EPS 1e-5f

using bf16x8 = __attribute__((ext_vector_type(8))) short;
using f32x4  = __attribute__((ext_vector_type(4))) float;

// ================= small helpers =================
__device__ __forceinline__ float waveReduce(float v) {
  #pragma unroll
  for (int o = 32; o > 0; o >>= 1) v += __shfl_down(v, o);
  return v;
}
__device__ __forceinline__ short f2bf(float f) {   // RNE fp32 -> bf16
  uint32_t u = __float_as_uint(f);
  return (short)((u + 0x7FFFu + ((u >> 16) & 1u)) >> 16);
}
__device__ __forceinline__ float bf2f(uint32_t h) { return __uint_as_float(h << 16); }
__device__ __forceinline__ uint32_t pk2(float a, float b) {
  return ((uint32_t)(uint16_t)f2bf(a)) | ((uint32_t)(uint16_t)f2bf(b) << 16);
}

// ================= D1: pack weights + zero ws + gather-idx ================
struct PackDesc { const float* src; short* dst; int K, Nr, nt; };
struct PackArgs { PackDesc d[14]; };

__global__ void __launch_bounds__(256)
k_pack_zero(PackArgs pa,
            const float* __restrict__ fc1w, const float* __restrict__ fc1b,
            const float* __restrict__ fc2w, const float* __restrict__ fc2b,
            const float* __restrict__ fc3w, const float* __restrict__ fc3b,
            float* __restrict__ attEffs,
            uint4* __restrict__ zb, int zq,
            const int* __restrict__ ci0, const int* __restrict__ ci1,
            const int* __restrict__ p2img,
            int* __restrict__ idx0, int* __restrict__ idx1) {
  int bid = blockIdx.x;
  if (bid >= 384) {                              // idx rider: [384, 384+2*NBLK_IDX)
    bid -= 384;
    if (bid < NBLK_IDX) {
      int i = bid * 256 + threadIdx.x;
      if (i < NIMG) idx0[i] = ci0[(i >= Mm ? NPp : 0) + p2img[i]];
    } else {
      int i = (bid - NBLK_IDX) * 256 + threadIdx.x;
      if (i < NIMG) idx1[i] = ci1[(i >= Mm ? NPp : 0) + p2img[i]];
    }
    return;
  }
  if (bid >= 128) {                              // zero rider: [128,384)
    const uint4 z = make_uint4(0u, 0u, 0u, 0u);
    int i = (bid - 128) * 256 + threadIdx.x;
    for (; i < zq; i += 256 * 256) zb[i] = z;
    return;
  }
  const int stride = 128 * 256;
  for (int di = 0; di < 14; di++) {
    const float* src = pa.d[di].src;
    short* dst = pa.d[di].dst;
    int K = pa.d[di].K, Nr = pa.d[di].Nr, ntiles = pa.d[di].nt;
    int total = (K / 32) * ntiles * 512;
    for (int idx = bid * 256 + threadIdx.x; idx < total; idx += stride) {
      int j = idx & 7, lane = (idx >> 3) & 63, tile = idx >> 9;
      int nt = tile % ntiles, kt = tile / ntiles;
      int k = kt * 32 + (lane >> 4) * 8 + j;
      int n = nt * 16 + (lane & 15);
      float v = (n < Nr) ? src[(size_t)k * Nr + n] : 0.f;
      dst[idx] = f2bf(v);
    }
  }
  if (bid < 2 && threadIdx.x < 64) {
    int s = bid, t = threadIdx.x;
    const float* f1w = fc1w + s * 64 * 16; const float* f1b = fc1b + s * 16;
    const float* f2w = fc2w + s * 64 * 16; const float* f2b = fc2b + s * 16;
    const float* f3w = fc3w + s * 64;      const float* f3b = fc3b + s * 2;
    float* aE = attEffs + s * 320;
    float p0 = 0.f, p1 = 0.f, v0 = 0.f, v1 = 0.f;
    #pragma unroll
    for (int j = 0; j < 16; j++) {
      p0 = fmaf(f1w[t * 16 + j], f3w[j * 2], p0);
      p1 = fmaf(f1w[t * 16 + j], f3w[j * 2 + 1], p1);
      v0 = fmaf(f2w[t * 16 + j], f3w[(16 + j) * 2], v0);
      v1 = fmaf(f2w[t * 16 + j], f3w[(16 + j) * 2 + 1], v1);
    }
    aE[t * 2] = p0; aE[t * 2 + 1] = p1;
    aE[128 + t * 2] = v0; aE[128 + t * 2 + 1] = v1;
    if (t == 0) {
      float b0 = f3b[0], b1 = f3b[1];
      for (int j = 0; j < 16; j++) {
        b0 += f1b[j] * f3w[j * 2] + f2b[j] * f3w[(16 + j) * 2];
        b1 += f1b[j] * f3w[j * 2 + 1] + f2b[j] * f3w[(16 + j) * 2 + 1];
      }
      aE[256] = b0; aE[257] = b1;
    }
  }
}

// ====== Lovász scan+bin body (register-resident) ===========================
__device__ void scanbin_body(const uint32_t* __restrict__ Hb, const uint32_t* __restrict__ HFb,
                             int n, int call, float* __restrict__ lossesC5,
                             int* __restrict__ gts5, int cls) {
  __shared__ int sWC[4], sWF[4];
  __shared__ float sRedF[4];
  int t = threadIdx.x;
  int lane = t & 63, w = t >> 6;
  const uint32_t* Hc  = Hb  + (size_t)cls * NB;
  const uint32_t* HFc = HFb + (size_t)cls * NB;
  int locC = 0, locF = 0;
  #pragma unroll
  for (int i = 0; i < 8; i++) {
    uint4 cv = *(const uint4*)(Hc  + t * 32 + i * 4);
    uint4 fv = *(const uint4*)(HFc + t * 32 + i * 4);
    locC += (int)(cv.x + cv.y + cv.z + cv.w);
    locF += (int)(fv.x + fv.y + fv.z + fv.w);
  }
  int sc = locC, sf = locF;
  #pragma unroll
  for (int o = 1; o < 64; o <<= 1) {
    int a = __shfl_up(sc, o);
    int b = __shfl_up(sf, o);
    if (lane >= o) { sc += a; sf += b; }
  }
  if (lane == 63) { sWC[w] = sc; sWF[w] = sf; }
  __syncthreads();
  int offC = 0, offF = 0, Ftot = 0;
  #pragma unroll
  for (int ww = 0; ww < 4; ww++) {
    int fc = sWF[ww];
    Ftot += fc;
    if (ww < w) { offC += sWC[ww]; offF += fc; }
  }
  int runC = offC + sc - locC;    // exclusive prefix (ascending bins)
  int runF = offF + sf - locF;
  float gts = (float)Ftot;
  float contrib = 0.f;
  #pragma unroll
  for (int i = 0; i < 8; i++) {
    uint4 cv = *(const uint4*)(Hc  + t * 32 + i * 4);
    uint4 fv = *(const uint4*)(HFc + t * 32 + i * 4);
    uint32_t ca[4] = {cv.x, cv.y, cv.z, cv.w};
    uint32_t fa[4] = {fv.x, fv.y, fv.z, fv.w};
    #pragma unroll
    for (int j = 0; j < 4; j++) {
      int cnt = (int)ca[j], fgc = (int)fa[j];
      runC += cnt; runF += fgc;                          // ascending inclusive
      if (cnt > 0 && Ftot > 0) {
        float r0 = (float)(n - runC);
        float F0 = (float)(Ftot - runF);
        float r1 = r0 + (float)cnt;
        float F1 = F0 + (float)fgc;
        float emean = __uint_as_float((uint32_t)(t * 32 + i * 4 + j) << 17);
        contrib += emean * (r1 / (gts + r1 - F1) - r0 / (gts + r0 - F0));
      }
    }
  }
  contrib = waveReduce(contrib);
  if (lane == 0) sRedF[w] = contrib;
  __syncthreads();
  if (t == 0) {
    lossesC5[call * 32 + cls] = (Ftot > 0) ? (sRedF[0] + sRedF[1] + sRedF[2] + sRedF[3]) : 0.f;
    gts5[call * 32 + cls] = Ftot;
  }
}

// ================= MFMA MLP core: relu(X@W1+b1)@W2+b2 ====================
template<int D>
__device__ __forceinline__ void mfma_mlp_body(const short* sXb, short* sH,
    int r0, int rows,
    const short* __restrict__ pw1, const float* __restrict__ B1,
    const short* __restrict__ pw2, const float* __restrict__ B2,
    float* __restrict__ Out) {
  constexpr int LDB = D + 8;
  constexpr int KT1 = D / 32;
  const int t = threadIdx.x;
  const int lane = t & 63, w = t >> 6;
  const int m = lane & 15, quad = lane >> 4;
  const int rowA = 16 * w + m;
  bf16x8 a1[KT1];
  #pragma unroll
  for (int kt = 0; kt < KT1; kt++)
    a1[kt] = *(const bf16x8*)(sXb + rowA * LDB + kt * 32 + quad * 8);
  const bf16x8* b1 = (const bf16x8*)pw1;
  #pragma unroll
  for (int nt = 0; nt < 8; nt++) {
    f32x4 c = {0.f, 0.f, 0.f, 0.f};
    #pragma unroll
    for (int kt = 0; kt < KT1; kt++)
      c = __builtin_amdgcn_mfma_f32_16x16x32_bf16(a1[kt], b1[(kt * 8 + nt) * 64 + lane], c, 0, 0, 0);
    int col = nt * 16 + m;
    float bc = B1[col];
    #pragma unroll
    for (int reg = 0; reg < 4; reg++)
      sH[(16 * w + quad * 4 + reg) * 136 + col] = f2bf(fmaxf(c[reg] + bc, 0.f));
  }
  __syncthreads();
  bf16x8 a2[4];
  #pragma unroll
  for (int kt = 0; kt < 4; kt++)
    a2[kt] = *(const bf16x8*)(sH + rowA * 136 + kt * 32 + quad * 8);
  const bf16x8* b2 = (const bf16x8*)pw2;
  #pragma unroll
  for (int nt = 0; nt < 2; nt++) {
    f32x4 c = {0.f, 0.f, 0.f, 0.f};
    #pragma unroll
    for (int kt = 0; kt < 4; kt++)
      c = __builtin_amdgcn_mfma_f32_16x16x32_bf16(a2[kt], b2[(kt * 2 + nt) * 64 + lane], c, 0, 0, 0);
    int col = nt * 16 + m;
    if (col < Cc) {
      float bc = B2[col];
      #pragma unroll
      for (int reg = 0; reg < 4; reg++) {
        int gr = r0 + 16 * w + quad * 4 + reg;
        if (gr < rows) Out[(size_t)gr * Cc + col] = c[reg] + bc;
      }
    }
  }
}

// ---- MLP D=64, f32 staging ----
__device__ void mlp64_body(int bid0, const float* __restrict__ X,
    const short* __restrict__ pw1, const float* __restrict__ B1,
    const short* __restrict__ pw2, const float* __restrict__ B2,
    float* __restrict__ Out, int rows, char* smem) {
  short* sXb = (short*)smem;              // 64*72
  short* sH  = (short*)(smem + 9216);     // 64*136
  int t = threadIdx.x, r0 = bid0 * 64;
  for (int i = t; i < 1024; i += 256) {
    int r = i >> 4, k4 = (i & 15) * 4;
    int gr = r0 + r;
    float4 v = (gr < rows) ? *(const float4*)(X + (size_t)gr * 64 + k4)
                           : make_float4(0.f, 0.f, 0.f, 0.f);
    uint2 p; p.x = pk2(v.x, v.y); p.y = pk2(v.z, v.w);
    *(uint2*)(sXb + r * 72 + k4) = p;
  }
  __syncthreads();
  mfma_mlp_body<64>(sXb, sH, r0, rows, pw1, B1, pw2, B2, Out);
}

// ---- MLP D=128, bf16 staging ----
__device__ void mlp128_body(int bid0, const uint16_t* __restrict__ Xh,
    const short* __restrict__ pw1, const float* __restrict__ B1,
    const short* __restrict__ pw2, const float* __restrict__ B2,
    float* __restrict__ Out, char* smem) {
  short* sXb = (short*)smem;              // 64*136
  short* sH  = (short*)(smem + 17408);    // 64*136
  int t = threadIdx.x, r0 = bid0 * 64;
  for (int i = t; i < 2048; i += 256) {
    int r = i >> 5, k4 = (i & 31) * 4;
    int gr = r0 + r;
    uint2 p = (gr < NIMG) ? *(const uint2*)(Xh + (size_t)gr * 128 + k4) : make_uint2(0u, 0u);
    *(uint2*)(sXb + r * 136 + k4) = p;
  }
  __syncthreads();
  mfma_mlp_body<128>(sXb, sH, r0, NIMG, pw1, B1, pw2, B2, Out);
}

// ---- voxel-vote counts ----
__device__ void cnt_body(int bid0, const int* __restrict__ ci, const int* __restrict__ labels,
                         int* __restrict__ counts) {
  int i = bid0 * 256 + threadIdx.x;
  if (i < NPT) atomicAdd(&counts[(size_t)ci[i] * Cc + labels[i]], 1);
}

// ---- BN partials column-reduce ----
__device__ void colred_body(int bid0, const float* __restrict__ partials,
                            float* __restrict__ red64) {
  int t = threadIdx.x, j = bid0;
  float v = 0.f;
  for (int b = j; b < NBLK_GA; b += 64) v += partials[(size_t)b * 256 + t];
  red64[j * 256 + t] = v;
}

// ---- Lovász fill body (CE + optional KL + optional voxel-vote) ----
__device__ void fill_body(int bid0, const float* __restrict__ logits,
                          const int* __restrict__ lab, const int* __restrict__ vcnt,
                          int n, uint16_t* __restrict__ E,
                          float ceScale, float* __restrict__ lossAcc,
                          const float* __restrict__ pred3d, const int* __restrict__ idxg,
                          float klScale) {
  int i = bid0 * 256 + threadIdx.x;
  float total = 0.f;
  if (i < n) {
    int lb;
    if (vcnt) {
      const int* crow = vcnt + (size_t)i * Cc;
      int best = crow[0], arg = 0;
      #pragma unroll
      for (int k = 1; k < Cc; k++) {
        int ck = crow[k];
        if (ck > best) { best = ck; arg = k; }   // first-max
      }
      lb = arg;
    } else {
      lb = lab[i];
    }
    const float* l = logits + (size_t)i * Cc;
    float m = l[0];
    #pragma unroll
    for (int c = 1; c < Cc; c++) m = fmaxf(m, l[c]);
    float ex[Cc]; float se = 0.f;
    #pragma unroll
    for (int c = 0; c < Cc; c++) { ex[c] = expf(l[c] - m); se += ex[c]; }
    float inv = 1.f / se;
    float lse = logf(se);
    total = -(l[lb] - m - lse) * ceScale;
    #pragma unroll
    for (int c = 0; c < Cc; c++) {
      float prob = ex[c] * inv;
      int fg = (c == lb) ? 1 : 0;
      float err = fg ? (1.f - prob) : prob;
      err = fmaxf(err, 0.f);
      uint32_t key = __float_as_uint(err) >> 17;     // < 8192
      E[(size_t)c * n + i] = (uint16_t)((key << 1) | (uint32_t)fg);
    }
    if (pred3d) {
      const float* q = pred3d + (size_t)idxg[i] * Cc;
      float mq = q[0];
      #pragma unroll
      for (int c = 1; c < Cc; c++) mq = fmaxf(mq, q[c]);
      float sq = 0.f;
      #pragma unroll
      for (int c = 0; c < Cc; c++) sq += expf(q[c] - mq);
      float lsq = logf(sq);
      float kl = 0.f;
      #pragma unroll
      for (int c = 0; c < Cc; c++) {
        float lf = l[c] - m - lse;
        float pf = ex[c] * inv;
        float lq = q[c] - mq - lsq;
        kl += pf * (lf - lq);
      }
      total += kl * klScale;
    }
  }
  total = waveReduce(total);
  __shared__ float sh[4];
  int lane = threadIdx.x & 63, w = threadIdx.x >> 6;
  if (lane == 0) sh[w] = total;
  __syncthreads();
  if (threadIdx.x == 0) atomicAdd(lossAcc, sh[0] + sh[1] + sh[2] + sh[3]);
}

// ---- LDS-privatized histogram body (256 threads) ----
__device__ void hist_body(int bid0, const uint16_t* __restrict__ E, int n,
                          uint32_t* __restrict__ H, uint32_t* __restrict__ HF, char* smem) {
  uint32_t* lcf = (uint32_t*)smem;                 // 8192 u32 = 32 KB
  int t = threadIdx.x;
  int cls = bid0 / NCH, ch = bid0 - cls * NCH;
  int CHsz = (n + NCH - 1) / NCH;
  int i0 = ch * CHsz;
  int i1 = min(n, i0 + CHsz);
  for (int b = t; b < NB; b += 256) lcf[b] = 0u;
  __syncthreads();
  const uint16_t* Ec = E + (size_t)cls * n;
  for (int i = i0 + t; i < i1; i += 256) {
    uint32_t p = Ec[i];
    atomicAdd(&lcf[p >> 1], 0x10000u | (p & 1u));    // count hi16, fg lo16
  }
  __syncthreads();
  uint32_t* Hc  = H  + (size_t)cls * NB;
  uint32_t* HFc = HF + (size_t)cls * NB;
  for (int b = t; b < NB; b += 256) {
    uint32_t v = lcf[b];
    if (v) {
      atomicAdd(&Hc[b], v >> 16);
      uint32_t f = v & 0xFFFFu;
      if (f) atomicAdd(&HFc[b], f);
    }
  }
}

// ---- gather + dual 64x64 GEMM + att + per-block BN partials ----
__device__ void gatt_body(int bid0, const float* __restrict__ pts, const int* __restrict__ idx,
                          const float* __restrict__ img,
                          const short* __restrict__ pc1, const float* __restrict__ c1b,
                          const short* __restrict__ pc2, const float* __restrict__ c2b,
                          const float* __restrict__ attEff,
                          uint16_t* __restrict__ y1, uint16_t* __restrict__ y2,
                          float* __restrict__ attw, float* __restrict__ partials,
                          char* smem) {
  short* sP = (short*)smem;                         // 64*72
  short* sV = (short*)(smem + 9216);                // 64*72
  float* sAtt  = (float*)(smem + 18432);            // 64*8
  float* sStat = (float*)(smem + 20480);            // 1024
  int t = threadIdx.x;
  int r0 = bid0 * 64;
  for (int i = t; i < 1024; i += 256) {
    int r = i >> 4, q = i & 15;
    int gr = r0 + r;
    float4 vp = make_float4(0.f, 0.f, 0.f, 0.f), vv = vp;
    if (gr < NIMG) {
      vp = *(const float4*)(pts + (size_t)idx[gr] * 64 + q * 4);
      vv = *(const float4*)(img + (size_t)gr * 64 + q * 4);
    }
    uint2 pp, qv;
    pp.x = pk2(vp.x, vp.y); pp.y = pk2(vp.z, vp.w);
    qv.x = pk2(vv.x, vv.y); qv.y = pk2(vv.z, vv.w);
    *(uint2*)(sP + r * 72 + q * 4) = pp;
    *(uint2*)(sV + r * 72 + q * 4) = qv;
  }
  __syncthreads();
  {
    int r = t & 63, qq = t >> 6;
    const float* aP = attEff;
    const float* aV = attEff + 128;
    float l0 = 0.f, l1 = 0.f;
    for (int k = qq * 16; k < qq * 16 + 16; k += 4) {
      uint2 up = *(const uint2*)(sP + r * 72 + k);
      uint2 uv = *(const uint2*)(sV + r * 72 + k);
      float p0 = bf2f(up.x & 0xffff), p1 = bf2f(up.x >> 16);
      float p2 = bf2f(up.y & 0xffff), p3 = bf2f(up.y >> 16);
      float v0 = bf2f(uv.x & 0xffff), v1 = bf2f(uv.x >> 16);
      float v2 = bf2f(uv.y & 0xffff), v3 = bf2f(uv.y >> 16);
      float4 wa = *(const float4*)(aP + 2 * k);
      float4 wb = *(const float4*)(aP + 2 * k + 4);
      l0 += p0 * wa.x + p1 * wa.z + p2 * wb.x + p3 * wb.z;
      l1 += p0 * wa.y + p1 * wa.w + p2 * wb.y + p3 * wb.w;
      float4 ua = *(const float4*)(aV + 2 * k);
      float4 ub = *(const float4*)(aV + 2 * k + 4);
      l0 += v0 * ua.x + v1 * ua.z + v2 * ub.x + v3 * ub.z;
      l1 += v0 * ua.y + v1 * ua.w + v2 * ub.y + v3 * ub.w;
    }
    sAtt[r * 8 + qq * 2] = l0;
    sAtt[r * 8 + qq * 2 + 1] = l1;
  }
  const int lane = t & 63, w = t >> 6;
  const int m = lane & 15, quad = lane >> 4;
  const int rowA = 16 * w + m;
  bf16x8 ap[2], av[2];
  #pragma unroll
  for (int kt = 0; kt < 2; kt++) {
    ap[kt] = *(const bf16x8*)(sP + rowA * 72 + kt * 32 + quad * 8);
    av[kt] = *(const bf16x8*)(sV + rowA * 72 + kt * 32 + quad * 8);
  }
  const bf16x8* b1 = (const bf16x8*)pc1;
  const bf16x8* b2 = (const bf16x8*)pc2;
  #pragma unroll
  for (int nt = 0; nt < 4; nt++) {
    int col = nt * 16 + m;
    f32x4 c1 = {0.f, 0.f, 0.f, 0.f}, c2 = {0.f, 0.f, 0.f, 0.f};
    #pragma unroll
    for (int kt = 0; kt < 2; kt++) {
      c1 = __builtin_amdgcn_mfma_f32_16x16x32_bf16(ap[kt], b1[(kt * 4 + nt) * 64 + lane], c1, 0, 0, 0);
      c2 = __builtin_amdgcn_mfma_f32_16x16x32_bf16(av[kt], b2[(kt * 4 + nt) * 64 + lane], c2, 0, 0, 0);
    }
    float bb1 = c1b[col], bb2 = c2b[col];
    float s1 = 0.f, q1 = 0.f, s2 = 0.f, q2 = 0.f;
    #pragma unroll
    for (int reg = 0; reg < 4; reg++) {
      int gr = r0 + 16 * w + quad * 4 + reg;
      if (gr < NIMG) {
        float v1 = c1[reg] + bb1, v2 = c2[reg] + bb2;
        y1[(size_t)gr * 64 + col] = (uint16_t)f2bf(v1);
        y2[(size_t)gr * 64 + col] = (uint16_t)f2bf(v2);
        s1 += v1; q1 = fmaf(v1, v1, q1);
        s2 += v2; q2 = fmaf(v2, v2, q2);
      }
    }
    s1 += __shfl_down(s1, 32); s1 += __shfl_down(s1, 16);
    q1 += __shfl_down(q1, 32); q1 += __shfl_down(q1, 16);
    s2 += __shfl_down(s2, 32); s2 += __shfl_down(s2, 16);
    q2 += __shfl_down(q2, 32); q2 += __shfl_down(q2, 16);
    if (lane < 16) {
      float* base = sStat + (w * 4 + nt) * 64 + lane;
      base[0]  = s1;
      base[16] = q1;
      base[32] = s2;
      base[48] = q2;
    }
  }
  __syncthreads();
  {
    int kind = t >> 6, col = t & 63;
    int nt = col >> 4, mm = col & 15;
    float v = 0.f;
    #pragma unroll
    for (int ww = 0; ww < 4; ww++)
      v += sStat[(ww * 4 + nt) * 64 + kind * 16 + mm];
    partials[(size_t)bid0 * 256 + kind * 64 + col] = v;
  }
  if (t < 64) {
    int gr = r0 + t;
    if (gr < NIMG) {
      float l0 = attEff[256] + sAtt[t * 8] + sAtt[t * 8 + 2] + sAtt[t * 8 + 4] + sAtt[t * 8 + 6];
      float l1 = attEff[257] + sAtt[t * 8 + 1] + sAtt[t * 8 + 3] + sAtt[t * 8 + 5] + sAtt[t * 8 + 7];
      attw[gr * 2]     = 1.f / (1.f + expf(-l0));
      attw[gr * 2 + 1] = 1.f / (1.f + expf(-l1));
    }
  }
}

// ---- fuse (BN from red64, inline) -> feats + fuse-MLP ----
__device__ void fusemlp_body(int bid0,
    const uint16_t* __restrict__ y1, const uint16_t* __restrict__ y2,
    const float* __restrict__ attw, const float* __restrict__ red64,
    const float* __restrict__ g1, const float* __restrict__ be1,
    const float* __restrict__ g2, const float* __restrict__ be2,
    uint16_t* __restrict__ feats, int s64,
    const short* __restrict__ pw1, const float* __restrict__ B1,
    const short* __restrict__ pw2, const float* __restrict__ B2,
    float* __restrict__ Out, char* smem) {
  short* sXb = (short*)smem;                    // 64*72
  short* sH  = (short*)(smem + 9216);           // 64*136
  float* sBn = (float*)(smem + 9216 + 17408);   // 256 floats
  int t = threadIdx.x, r0 = bid0 * 64;
  float acc = 0.f;
  #pragma unroll 8
  for (int b = 0; b < 64; b++) acc += red64[b * 256 + t];
  float* sSum = (float*)sH;                     // scratch
  sSum[t] = acc;
  __syncthreads();
  if (t < 64) {
    float nn = (float)NIMG;
    float mu1 = sSum[t] / nn;
    float var1 = sSum[64 + t] / nn - mu1 * mu1;
    float a1 = g1[t] / sqrtf(var1 + BN_EPS);
    sBn[t] = a1; sBn[64 + t] = be1[t] - mu1 * a1;
    float mu2 = sSum[128 + t] / nn;
    float var2 = sSum[192 + t] / nn - mu2 * mu2;
    float a2 = g2[t] / sqrtf(var2 + BN_EPS);
    sBn[128 + t] = a2; sBn[192 + t] = be2[t] - mu2 * a2;
  }
  __syncthreads();
  for (int i = t; i < 1024; i += 256) {
    int r = i >> 4, q = i & 15;
    int gr = r0 + r;
    uint2 zp = make_uint2(0u, 0u);
    if (gr < NIMG) {
      float4 a1 = *(const float4*)(sBn + q * 4);
      float4 c1 = *(const float4*)(sBn + 64 + q * 4);
      float4 a2 = *(const float4*)(sBn + 128 + q * 4);
      float4 c2 = *(const float4*)(sBn + 192 + q * 4);
      uint2 u1 = *(const uint2*)(y1 + (size_t)gr * 64 + q * 4);
      uint2 u2 = *(const uint2*)(y2 + (size_t)gr * 64 + q * 4);
      float w0 = attw[gr * 2], w1 = attw[gr * 2 + 1];
      float zx = fmaxf(fmaf(bf2f(u1.x & 0xffff), a1.x, c1.x), 0.f) * w0
               + fmaxf(fmaf(bf2f(u2.x & 0xffff), a2.x, c2.x), 0.f) * w1;
      float zy = fmaxf(fmaf(bf2f(u1.x >> 16),   a1.y, c1.y), 0.f) * w0
               + fmaxf(fmaf(bf2f(u2.x >> 16),   a2.y, c2.y), 0.f) * w1;
      float zz = fmaxf(fmaf(bf2f(u1.y & 0xffff), a1.z, c1.z), 0.f) * w0
               + fmaxf(fmaf(bf2f(u2.y & 0xffff), a2.z, c2.z), 0.f) * w1;
      float zw = fmaxf(fmaf(bf2f(u1.y >> 16),   a1.w, c1.w), 0.f) * w0
               + fmaxf(fmaf(bf2f(u2.y >> 16),   a2.w, c2.w), 0.f) * w1;
      zp.x = pk2(zx, zy); zp.y = pk2(zz, zw);
      *(uint2*)(feats + (size_t)gr * 128 + s64 + q * 4) = zp;
    }
    *(uint2*)(sXb + r * 72 + q * 4) = zp;
  }
  __syncthreads();
  mfma_mlp_body<64>(sXb, sH, r0, NIMG, pw1, B1, pw2, B2, Out);
}

// ===================== wrapper kernels (block-range bundles) ===============
// D2: gatt(s0) + gatt(s1) + pred3d MLP x2 + counts x2
__global__ void __launch_bounds__(256)
k_mega2(const float* __restrict__ pf0, const float* __restrict__ pf1,
        const int* __restrict__ idx0, const int* __restrict__ idx1,
        const float* __restrict__ if0, const float* __restrict__ if1,
        const short* pc1w0, const short* pc1w1, const short* pc2w0, const short* pc2w1,
        const float* c1b, const float* c2b, const float* attEffs,
        uint16_t* y1a, uint16_t* y2a, uint16_t* y1b, uint16_t* y2b,
        float* attw0, float* attw1, float* partials0, float* partials1,
        const short* pw3a0, const float* b3a, const short* pw3b0, const float* b3b,
        const short* pw3a1, const short* pw3b1,
        float* pred3d0, float* pred3d1,
        const int* __restrict__ ci0, const int* __restrict__ ci1,
        const int* __restrict__ labels,
        int* __restrict__ counts0, int* __restrict__ counts1) {
  __shared__ char smem[26624];
  int bid = blockIdx.x;
  if (bid < NBLK_GA) {
    gatt_body(bid, pf0, idx0, if0, pc1w0, c1b, pc2w0, c2b, attEffs,
              y1a, y2a, attw0, partials0, smem);
    return;
  }
  bid -= NBLK_GA;
  if (bid < NBLK_GA) {
    gatt_body(bid, pf1, idx1, if1, pc1w1, c1b + 64, pc2w1, c2b + 64, attEffs + 320,
              y1b, y2b, attw1, partials1, smem);
    return;
  }
  bid -= NBLK_GA;
  if (bid < NBLK_MLP) { mlp64_body(bid, pf0, pw3a0, b3a, pw3b0, b3b, pred3d0, NV, smem); return; }
  bid -= NBLK_MLP;
  if (bid < NBLK_MLP) { mlp64_body(bid, pf1, pw3a1, b3a + 128, pw3b1, b3b + Cc, pred3d1, NV, smem); return; }
  bid -= NBLK_MLP;
  if (bid < NBLK_CNT) { cnt_body(bid, ci0, labels, counts0); return; }
  cnt_body(bid - NBLK_CNT, ci1, labels, counts1);
}

// D3: fill2 (NV x2, vote inline) + colred x2
__global__ void __launch_bounds__(256)
k_fill_colred(const float* __restrict__ l0, const int* __restrict__ vc0, uint16_t* __restrict__ E0,
              const float* __restrict__ l1, const int* __restrict__ vc1, uint16_t* __restrict__ E1,
              float ce, float* __restrict__ lossAcc,
              const float* partials0, float* red64_0,
              const float* partials1, float* red64_1) {
  int bid = blockIdx.x;
  if (bid < NBLK_FILL_NV) {
    fill_body(bid, l0, nullptr, vc0, NV, E0, ce, lossAcc, nullptr, nullptr, 0.f);
    return;
  }
  bid -= NBLK_FILL_NV;
  if (bid < NBLK_FILL_NV) {
    fill_body(bid, l1, nullptr, vc1, NV, E1, ce, lossAcc, nullptr, nullptr, 0.f);
    return;
  }
  bid -= NBLK_FILL_NV;
  if (bid < 64) { colred_body(bid, partials0, red64_0); return; }
  colred_body(bid - 64, partials1, red64_1);
}

// D4: fusemlp x2 + hist(call0) + hist(call2)
__global__ void __launch_bounds__(256)
k_fuse2_hist2(const uint16_t* y1a, const uint16_t* y2a, const float* attw0, const float* red64_0,
              const uint16_t* y1b, const uint16_t* y2b, const float* attw1, const float* red64_1,
              const float* bn1g, const float* bn1b, const float* bn2g, const float* bn2b,
              uint16_t* feats,
              const short* pwfa0, const float* bfa, const short* pwfb0, const float* bfb,
              const short* pwfa1, const short* pwfb1,
              float* fusepred0, float* fusepred1,
              const uint16_t* __restrict__ E0, uint32_t* H0, uint32_t* HF0,
              const uint16_t* __restrict__ E1, uint32_t* H2, uint32_t* HF2) {
  __shared__ char smem[32768];
  int bid = blockIdx.x;
  if (bid < NBLK_GA) {
    fusemlp_body(bid, y1a, y2a, attw0, red64_0, bn1g, bn1b, bn2g, bn2b, feats, 0,
                 pwfa0, bfa, pwfb0, bfb, fusepred0, smem);
    return;
  }
  bid -= NBLK_GA;
  if (bid < NBLK_GA) {
    fusemlp_body(bid, y1b, y2b, attw1, red64_1, bn1g + 64, bn1b + 64, bn2g + 64, bn2b + 64,
                 feats, 64, pwfa1, bfa + 128, pwfb1, bfb + Cc, fusepred1, smem);
    return;
  }
  bid -= NBLK_GA;
  if (bid < NBLK_HIST) { hist_body(bid, E0, NV, H0, HF0, smem); return; }
  hist_body(bid - NBLK_HIST, E1, NV, H2, HF2, smem);
}

// D5: final MLP (D=128) + fill(call1) + fill(call3) + scan(call0) + scan(call2)
__global__ void __launch_bounds__(256)
k_finx2(const uint16_t* __restrict__ feats,
        const short* pcl1, const float* clb1, const short* pcl2, const float* clb2,
        float* finalpred,
        const float* fusepred0, const float* pred3d0, const int* idx0, uint16_t* E0w,
        const float* fusepred1, const float* pred3d1, const int* idx1, uint16_t* E1w,
        const int* __restrict__ img_label, float ce, float kl, float* lossAcc,
        const uint32_t* H0, const uint32_t* HF0,
        const uint32_t* H2, const uint32_t* HF2,
        float* lossesC5, int* gts5) {
  __shared__ char smem[34816];
  int bid = blockIdx.x;
  if (bid < NBLK_GA) { mlp128_body(bid, feats, pcl1, clb1, pcl2, clb2, finalpred, smem); return; }
  bid -= NBLK_GA;
  if (bid < NBLK_FILL_NI) {
    fill_body(bid, fusepred0, img_label, nullptr, NIMG, E0w, ce, lossAcc, pred3d0, idx0, kl);
    return;
  }
  bid -= NBLK_FILL_NI;
  if (bid < NBLK_FILL_NI) {
    fill_body(bid, fusepred1, img_label, nullptr, NIMG, E1w, ce, lossAcc, pred3d1, idx1, kl);
    return;
  }
  bid -= NBLK_FILL_NI;
  if (bid < Cc) { scanbin_body(H0, HF0, NV, 0, lossesC5, gts5, bid); return; }
  scanbin_body(H2, HF2, NV, 2, lossesC5, gts5, bid - Cc);
}

// D6: hist(call1) + hist(call3) + fill(call4)
__global__ void __launch_bounds__(256)
k_hist2_fill(const uint16_t* __restrict__ E0, uint32_t* H1, uint32_t* HF1,
             const uint16_t* __restrict__ E1, uint32_t* H3, uint32_t* HF3,
             const float* __restrict__ finalpred, const int* __restrict__ img_label,
             uint16_t* __restrict__ E2, float ce, float* lossAcc) {
  __shared__ char smem[32768];
  int bid = blockIdx.x;
  if (bid < NBLK_HIST) { hist_body(bid, E0, NIMG, H1, HF1, smem); return; }
  bid -= NBLK_HIST;
  if (bid < NBLK_HIST) { hist_body(bid, E1, NIMG, H3, HF3, smem); return; }
  fill_body(bid - NBLK_HIST, finalpred, img_label, nullptr, NIMG, E2, ce, lossAcc,
            nullptr, nullptr, 0.f);
}

// D7: hist(call4) + scan(call1) + scan(call3)
__global__ void __launch_bounds__(256)
k_hist_scan2(const uint16_t* __restrict__ E2, uint32_t* H4, uint32_t* HF4,
             const uint32_t* H1, const uint32_t* HF1,
             const uint32_t* H3, const uint32_t* HF3,
             float* lossesC5, int* gts5) {
  __shared__ char smem[32768];
  int bid = blockIdx.x;
  if (bid < NBLK_HIST) { hist_body(bid, E2, NIMG, H4, HF4, smem); return; }
  bid -= NBLK_HIST;
  if (bid < Cc) { scanbin_body(H1, HF1, NIMG, 1, lossesC5, gts5, bid); return; }
  scanbin_body(H3, HF3, NIMG, 3, lossesC5, gts5, bid - Cc);
}

// D8: scan(call4)
__global__ void __launch_bounds__(256)
k_scanbin5(const uint32_t* Hb, const uint32_t* HFb, int n, int call,
           float* lossesC5, int* gts5) {
  scanbin_body(Hb, HFb, n, call, lossesC5, gts5, blockIdx.x);
}

// D9: fold 5 lovász combines + output
__global__ void k_final(const float* __restrict__ lossAcc,
                        const float* __restrict__ lossesC5, const int* __restrict__ gts5,
                        float* __restrict__ out) {
  const float coefs[5] = {1.0f, 0.5f, 1.0f, 0.5f, 1.0f};
  float loss = lossAcc[0];
  for (int call = 0; call < 5; call++) {
    float s = 0.f; int np = 0;
    for (int c = 0; c < Cc; c++)
      if (gts5[call * 32 + c] > 0) { s += lossesC5[call * 32 + c]; np++; }
    loss += coefs[call] * s / (float)(np > 0 ? np : 1);
  }
  out[0] = loss;
}

// ================= host-side driver =================
extern "C" void kernel_launch(void* const* d_in, const int* in_sizes, int n_in,
                              void* d_out, int out_size, void* d_ws, size_t ws_size,
                              hipStream_t stream) {
  const float* img_feat = (const float*)d_in[0];
  const float* pts_feat = (const float*)d_in[1];
  const int* coors_inv  = (const int*)d_in[2];
  const int* labels     = (const int*)d_in[3];
  const int* img_label  = (const int*)d_in[4];
  const int* p2img      = (const int*)d_in[5];
  const float* w3a = (const float*)d_in[6];
  const float* b3a = (const float*)d_in[7];
  const float* w3b = (const float*)d_in[8];
  const float* b3b = (const float*)d_in[9];
  const float* wfa = (const float*)d_in[10];
  const float* bfa = (const float*)d_in[11];
  const float* wfb = (const float*)d_in[12];
  const float* bfb = (const float*)d_in[13];
  const float* fc1w = (const float*)d_in[14];
  const float* fc1b = (const float*)d_in[15];
  const float* fc2w = (const float*)d_in[16];
  const float* fc2b = (const float*)d_in[17];
  const float* fc3w = (const float*)d_in[18];
  const float* fc3b = (const float*)d_in[19];
  const float* c1w  = (const float*)d_in[20];
  const float* c1b  = (const float*)d_in[21];
  const float* bn1g = (const float*)d_in[22];
  const float* bn1b = (const float*)d_in[23];
  const float* c2w  = (const float*)d_in[24];
  const float* c2b  = (const float*)d_in[25];
  const float* bn2g = (const float*)d_in[26];
  const float* bn2b = (const float*)d_in[27];
  const float* clw1 = (const float*)d_in[28];
  const float* clb1 = (const float*)d_in[29];
  const float* clw2 = (const float*)d_in[30];
  const float* clb2 = (const float*)d_in[31];
  (void)in_sizes; (void)n_in; (void)out_size; (void)ws_size;

  // ---- workspace layout ----
  char* ws = (char*)d_ws;
  size_t off = 0;
  auto alloc = [&](size_t bytes) { void* p = ws + off; off += (bytes + 255) & ~(size_t)255; return p; };
  uint16_t* feats = (uint16_t*)alloc((size_t)NIMG * 128 * 2);
  float* pred3d0 = (float*)alloc((size_t)NV * Cc * 4);
  float* pred3d1 = (float*)alloc((size_t)NV * Cc * 4);
  int* idx0 = (int*)alloc((size_t)NIMG * 4);
  int* idx1 = (int*)alloc((size_t)NIMG * 4);
  uint16_t* y1a = (uint16_t*)alloc((size_t)NIMG * Hh * 2);
  uint16_t* y2a = (uint16_t*)alloc((size_t)NIMG * Hh * 2);
  uint16_t* y1b = (uint16_t*)alloc((size_t)NIMG * Hh * 2);
  uint16_t* y2b = (uint16_t*)alloc((size_t)NIMG * Hh * 2);
  uint16_t* E0 = (uint16_t*)alloc((size_t)Cc * NV * 2);
  uint16_t* E1 = (uint16_t*)alloc((size_t)Cc * NV * 2);
  uint16_t* E2 = (uint16_t*)alloc((size_t)Cc * NIMG * 2);
  float* partials0 = (float*)alloc((size_t)NBLK_GA * 256 * 4);
  float* partials1 = (float*)alloc((size_t)NBLK_GA * 256 * 4);
  float* red64_0 = (float*)alloc(64 * 256 * 4);
  float* red64_1 = (float*)alloc(64 * 256 * 4);
  float* attw0 = (float*)alloc((size_t)NIMG * 2 * 4);
  float* attw1 = (float*)alloc((size_t)NIMG * 2 * 4);
  float* fusepred0 = (float*)alloc((size_t)NIMG * Cc * 4);
  float* fusepred1 = (float*)alloc((size_t)NIMG * Cc * 4);
  float* finalpred = (float*)alloc((size_t)NIMG * Cc * 4);
  short* pwAll = (short*)alloc(86016 * 2);
  short* pw3a0 = pwAll,          * pw3a1 = pwAll + 8192;
  short* pwfa0 = pwAll + 16384,  * pwfa1 = pwAll + 24576;
  short* pw3b0 = pwAll + 32768,  * pw3b1 = pwAll + 36864;
  short* pwfb0 = pwAll + 40960,  * pwfb1 = pwAll + 45056;
  short* pcl1  = pwAll + 49152;
  short* pcl2  = pwAll + 65536;
  short* pc1w0 = pwAll + 69632,  * pc1w1 = pwAll + 73728;
  short* pc2w0 = pwAll + 77824,  * pc2w1 = pwAll + 81920;
  float* attEffs = (float*)alloc(2 * 320 * 4);
  // ---- contiguous zero region: stats + 5x(H,HF) + counts0/1 ----
  size_t zsize = 1024 + (size_t)5 * 2 * Cc * NB * 4 + (size_t)2 * NV * Cc * 4;
  char* zbase = (char*)alloc(zsize);
  float* lossAcc  = (float*)zbase;                 // [0]
  float* lossesC5 = (float*)zbase + 32;            // 5*32
  int*   gts5     = (int*)((float*)zbase + 192);   // 5*32 ints
  uint32_t* Hbase = (uint32_t*)(zbase + 1024);
  auto Hc  = [&](int call) { return Hbase + (size_t)call * 2 * Cc * NB; };
  auto HFc = [&](int call) { return Hbase + (size_t)call * 2 * Cc * NB + (size_t)Cc * NB; };
  int* counts0 = (int*)(zbase + 1024 + (size_t)5 * 2 * Cc * NB * 4);
  int* counts1 = counts0 + (size_t)NV * Cc;
  int zq = (int)(zsize / 16);

  const float kl = 0.025f / ((float)NIMG * Cc);
  const float* pf0 = pts_feat;
  const float* pf1 = pts_feat + (size_t)NV * Hh;
  const float* if0 = img_feat;
  const float* if1 = img_feat + (size_t)NIMG * Hh;
  const int* ci0 = coors_inv;
  const int* ci1 = coors_inv + NPT;

  // D1: pack weights + zero ws region + gather-idx x2
  PackArgs pa;
  pa.d[0]  = {w3a,        pw3a0, 64, 128, 8};
  pa.d[1]  = {w3a + 8192, pw3a1, 64, 128, 8};
  pa.d[2]  = {wfa,        pwfa0, 64, 128, 8};
  pa.d[3]  = {wfa + 8192, pwfa1, 64, 128, 8};
  pa.d[4]  = {w3b,        pw3b0, 128, 20, 2};
  pa.d[5]  = {w3b + 2560, pw3b1, 128, 20, 2};
  pa.d[6]  = {wfb,        pwfb0, 128, 20, 2};
  pa.d[7]  = {wfb + 2560, pwfb1, 128, 20, 2};
  pa.d[8]  = {clw1,       pcl1, 128, 128, 8};
  pa.d[9]  = {clw2,       pcl2, 128, 20, 2};
  pa.d[10] = {c1w,        pc1w0, 64, 64, 4};
  pa.d[11] = {c1w + 4096, pc1w1, 64, 64, 4};
  pa.d[12] = {c2w,        pc2w0, 64, 64, 4};
  pa.d[13] = {c2w + 4096, pc2w1, 64, 64, 4};
  k_pack_zero<<<384 + 2 * NBLK_IDX, 256, 0, stream>>>(
      pa, fc1w, fc1b, fc2w, fc2b, fc3w, fc3b, attEffs,
      (uint4*)zbase, zq, ci0, ci1, p2img, idx0, idx1);

  // D2: gatt x2 + pred3d MLP x2 + counts x2
  k_mega2<<<2 * NBLK_GA + 2 * NBLK_MLP + 2 * NBLK_CNT, 256, 0, stream>>>(
      pf0, pf1, idx0, idx1, if0, if1,
      pc1w0, pc1w1, pc2w0, pc2w1, c1b, c2b, attEffs,
      y1a, y2a, y1b, y2b, attw0, attw1, partials0, partials1,
      pw3a0, b3a, pw3b0, b3b, pw3a1, pw3b1, pred3d0, pred3d1,
      ci0, ci1, labels, counts0, counts1);

  // D3: fill2 (vote inline) + colred x2
  k_fill_colred<<<2 * NBLK_FILL_NV + 128, 256, 0, stream>>>(
      pred3d0, counts0, E0, pred3d1, counts1, E1, 1.0f / NV, lossAcc,
      partials0, red64_0, partials1, red64_1);

  // D4: fusemlp x2 (BN inline) + hist(call0) + hist(call2)
  k_fuse2_hist2<<<2 * NBLK_GA + 2 * NBLK_HIST, 256, 0, stream>>>(
      y1a, y2a, attw0, red64_0, y1b, y2b, attw1, red64_1,
      bn1g, bn1b, bn2g, bn2b, feats,
      pwfa0, bfa, pwfb0, bfb, pwfa1, pwfb1, fusepred0, fusepred1,
      E0, Hc(0), HFc(0), E1, Hc(2), HFc(2));

  // D5: final MLP + fill(call1) + fill(call3) + scan(call0) + scan(call2)
  k_finx2<<<NBLK_GA + 2 * NBLK_FILL_NI + 2 * Cc, 256, 0, stream>>>(
      feats, pcl1, clb1, pcl2, clb2, finalpred,
      fusepred0, pred3d0, idx0, E0,
      fusepred1, pred3d1, idx1, E1,
      img_label, 0.5f / NIMG, kl, lossAcc,
      Hc(0), HFc(0), Hc(2), HFc(2), lossesC5, gts5);

  // D6: hist(call1) + hist(call3) + fill(call4)
  k_hist2_fill<<<2 * NBLK_HIST + NBLK_FILL_NI, 256, 0, stream>>>(
      E0, Hc(1), HFc(1), E1, Hc(3), HFc(3),
      finalpred, img_label, E2, 1.0f / NIMG, lossAcc);

  // D7: hist(call4) + scan(call1) + scan(call3)
  k_hist_scan2<<<NBLK_HIST + 2 * Cc, 256, 0, stream>>>(
      E2, Hc(4), HFc(4), Hc(1), HFc(1), Hc(3), HFc(3), lossesC5, gts5);

  // D8: scan(call4)
  k_scanbin5<<<Cc, 256, 0, stream>>>(Hc(4), HFc(4), NIMG, 4, lossesC5, gts5);

  // D9: fold + output
  k_final<<<1, 1, 0, stream>>>(lossAcc, lossesC5, gts5, (float*)d_out);
}